// Round 3
// baseline (820.585 us; speedup 1.0000x reference)
//
#include <hip/hip_runtime.h>
#include <hip/hip_bf16.h>
#include <stdint.h>

typedef unsigned short ushort_t;
typedef unsigned int uint_t;

#define B_ 512
#define S_ 256
#define T_ 10
#define V_ 28
#define H_ 128

// ---- workspace layout (float element offsets) ----
// WT_F/WT_B hold the enc PACKED layout (float4-of-k per thread); WT_D transposed for dec.
#define XT_F   0
#define XT_B   14336
#define XT_D   28672
#define WT_F   43008
#define WT_B   108544
#define WT_D   174080
#define AWT    239616
#define OWT    272384
#define PWT    275968
#define HFIN   308736
#define CFIN   439808
#define HDEC   570880
#define FLOATS_END 1226240
#define HS_BYTE_OFF (1226240ull * 4ull)
#define PREP_N 308736

__device__ __forceinline__ float fast_exp2(float x) { return __builtin_amdgcn_exp2f(x); }
__device__ __forceinline__ float fast_rcp(float x)  { return __builtin_amdgcn_rcpf(x); }
__device__ __forceinline__ float sigm(float x) {
    return fast_rcp(1.f + fast_exp2(-1.4426950408889634f * x));
}
__device__ __forceinline__ float tanh_(float x) {
    return 1.f - 2.f * fast_rcp(1.f + fast_exp2(2.8853900817779268f * x));
}
__device__ __forceinline__ ushort_t f2bf(float x) {
    uint_t u = __float_as_uint(x);
    return (ushort_t)((u + 0x7FFFu + ((u >> 16) & 1u)) >> 16);  // RNE
}
__device__ __forceinline__ float bflo(uint_t u) { return __uint_as_float(u << 16); }
__device__ __forceinline__ float bfhi(uint_t u) { return __uint_as_float(u & 0xFFFF0000u); }

// ---------------- prep: xg tables + weight transposes/packs ----------------
__global__ __launch_bounds__(256) void prep_kernel(
    const float* __restrict__ embed,
    const float* __restrict__ Wih_f, const float* __restrict__ b_f,
    const float* __restrict__ Wih_b, const float* __restrict__ b_b,
    const float* __restrict__ Wih_d, const float* __restrict__ b_d,
    const float* __restrict__ Whh_f, const float* __restrict__ Whh_b,
    const float* __restrict__ Whh_d,
    const float* __restrict__ attn_W, const float* __restrict__ out_W,
    const float* __restrict__ proj_W,
    float* __restrict__ ws)
{
    int i = blockIdx.x * 256 + threadIdx.x;
    if (i < 43008) {                       // xg tables: table[v][j] = b[j] + sum_e embed[v,e]*Wih[j,e]
        int tbl = i / 14336, rem = i % 14336;
        int v = rem >> 9, jj = rem & 511;
        const float* Wih = (tbl == 0) ? Wih_f : (tbl == 1) ? Wih_b : Wih_d;
        const float* bb  = (tbl == 0) ? b_f   : (tbl == 1) ? b_b   : b_d;
        float acc = bb[jj];
        #pragma unroll
        for (int e = 0; e < 32; ++e) acc = fmaf(embed[v * 32 + e], Wih[jj * 32 + e], acc);
        ws[tbl * 14336 + rem] = acc;
    } else if (i < 43008 + 196608) {
        int r = i - 43008; int tbl = r / 65536; int rem = r % 65536;
        int k = rem >> 9, jj = rem & 511;
        const float* Whh = (tbl == 0) ? Whh_f : (tbl == 1) ? Whh_b : Whh_d;
        float val = Whh[jj * 128 + k];
        if (tbl == 2) {
            // dec: transposed WhhT[k][j]
            ws[WT_F + tbl * 65536 + k * 512 + jj] = val;
        } else {
            // enc: packed float4-of-k: Wp[(k>>2)*512 + j][k&3]
            ws[WT_F + tbl * 65536 + (((k >> 2) * 512 + jj) << 2) + (k & 3)] = val;
        }
    } else if (i < OWT) {                  // attn_WT[k][u] = attn_W[u][k]
        int r = i - AWT; int k = r >> 7, uu = r & 127;
        ws[AWT + k * 128 + uu] = attn_W[uu * 256 + k];
    } else if (i < PWT) {                  // out_WT[k][v] = out_W[v][k]
        int r = i - OWT; int k = r / 28, v = r % 28;
        ws[OWT + k * 28 + v] = out_W[v * 128 + k];
    } else if (i < HFIN) {                 // projWT[k][u] = proj_W[u][k]
        int r = i - PWT; int k = r >> 7, uu = r & 127;
        ws[PWT + k * 128 + uu] = proj_W[uu * 256 + k];
    }
}

// ---------------- encoder: 1024 thr = (512 gates) x (2 k-halves), 4 rows/block ----------------
// 16 NAMED float4 weight registers (64 VGPR), loaded once, coalesced dwordx4.
__global__ __launch_bounds__(1024, 4) void enc_kernel(
    const int* __restrict__ src,
    const float* __restrict__ xt_base,
    const float* __restrict__ wt_base,
    float* __restrict__ hfin_base,
    float* __restrict__ cfin_base,
    ushort_t* __restrict__ hs)
{
    const int dir = blockIdx.y;
    const int b0 = blockIdx.x * 4;
    const int tid = threadIdx.x;
    const int j = tid & 511, kh = tid >> 9;
    const int kh64 = kh << 6;

    const float* xt = xt_base + dir * 14336;
    const float4* __restrict__ Wp =
        reinterpret_cast<const float4*>(wt_base + dir * 65536);
    const int wbase = (kh << 4) * 512 + j;

    __shared__ __align__(16) float parts[2][4][512];
    __shared__ __align__(16) float h_lds[4][128];
    __shared__ int tok_lds[4][256];

    for (int i = tid; i < 4 * 256; i += 1024)
        tok_lds[i >> 8][i & 255] = src[(b0 + (i >> 8)) * S_ + (i & 255)];
    if (tid < 512) h_lds[tid >> 7][tid & 127] = 0.f;

    const float4 w00 = Wp[wbase +  0 * 512];
    const float4 w01 = Wp[wbase +  1 * 512];
    const float4 w02 = Wp[wbase +  2 * 512];
    const float4 w03 = Wp[wbase +  3 * 512];
    const float4 w04 = Wp[wbase +  4 * 512];
    const float4 w05 = Wp[wbase +  5 * 512];
    const float4 w06 = Wp[wbase +  6 * 512];
    const float4 w07 = Wp[wbase +  7 * 512];
    const float4 w08 = Wp[wbase +  8 * 512];
    const float4 w09 = Wp[wbase +  9 * 512];
    const float4 w10 = Wp[wbase + 10 * 512];
    const float4 w11 = Wp[wbase + 11 * 512];
    const float4 w12 = Wp[wbase + 12 * 512];
    const float4 w13 = Wp[wbase + 13 * 512];
    const float4 w14 = Wp[wbase + 14 * 512];
    const float4 w15 = Wp[wbase + 15 * 512];
    __syncthreads();

    float xa0 = 0.f, xa1 = 0.f, xa2 = 0.f, xa3 = 0.f;
    {
        int p0 = dir ? (S_ - 1) : 0;
        if (kh == 0) {
            xa0 = xt[tok_lds[0][p0] * 512 + j];
            xa1 = xt[tok_lds[1][p0] * 512 + j];
            xa2 = xt[tok_lds[2][p0] * 512 + j];
            xa3 = xt[tok_lds[3][p0] * 512 + j];
        }
    }
    float c = 0.f, hlast = 0.f;

    for (int t = 0; t < S_; ++t) {
        float a0 = xa0, a1 = xa1, a2 = xa2, a3 = xa3;
        if (t + 1 < S_ && kh == 0) {           // prefetch next step's xg
            int pn = dir ? (S_ - 2 - t) : (t + 1);
            xa0 = xt[tok_lds[0][pn] * 512 + j];
            xa1 = xt[tok_lds[1][pn] * 512 + j];
            xa2 = xt[tok_lds[2][pn] * 512 + j];
            xa3 = xt[tok_lds[3][pn] * 512 + j];
        }
        #define KC(i, W) { const float4 w = (W); \
            const float4 h0 = *reinterpret_cast<const float4*>(&h_lds[0][kh64 + (i) * 4]); \
            const float4 h1 = *reinterpret_cast<const float4*>(&h_lds[1][kh64 + (i) * 4]); \
            const float4 h2 = *reinterpret_cast<const float4*>(&h_lds[2][kh64 + (i) * 4]); \
            const float4 h3 = *reinterpret_cast<const float4*>(&h_lds[3][kh64 + (i) * 4]); \
            a0 = fmaf(h0.x, w.x, a0); a0 = fmaf(h0.y, w.y, a0); a0 = fmaf(h0.z, w.z, a0); a0 = fmaf(h0.w, w.w, a0); \
            a1 = fmaf(h1.x, w.x, a1); a1 = fmaf(h1.y, w.y, a1); a1 = fmaf(h1.z, w.z, a1); a1 = fmaf(h1.w, w.w, a1); \
            a2 = fmaf(h2.x, w.x, a2); a2 = fmaf(h2.y, w.y, a2); a2 = fmaf(h2.z, w.z, a2); a2 = fmaf(h2.w, w.w, a2); \
            a3 = fmaf(h3.x, w.x, a3); a3 = fmaf(h3.y, w.y, a3); a3 = fmaf(h3.z, w.z, a3); a3 = fmaf(h3.w, w.w, a3); }
        KC(0,  w00) KC(1,  w01) KC(2,  w02) KC(3,  w03)
        KC(4,  w04) KC(5,  w05) KC(6,  w06) KC(7,  w07)
        KC(8,  w08) KC(9,  w09) KC(10, w10) KC(11, w11)
        KC(12, w12) KC(13, w13) KC(14, w14) KC(15, w15)
        #undef KC
        parts[kh][0][j] = a0; parts[kh][1][j] = a1;
        parts[kh][2][j] = a2; parts[kh][3][j] = a3;
        __syncthreads();
        if (tid < 512) {
            int r = tid >> 7, u = tid & 127;
            int pos = dir ? (S_ - 1 - t) : t;
            float gi = parts[0][r][u]       + parts[1][r][u];
            float gf = parts[0][r][u + 128] + parts[1][r][u + 128];
            float gg = parts[0][r][u + 256] + parts[1][r][u + 256];
            float go = parts[0][r][u + 384] + parts[1][r][u + 384];
            float ii = sigm(gi), ff = sigm(gf), g_ = tanh_(gg), oo = sigm(go);
            c = ff * c + ii * g_;
            float h = oo * tanh_(c);
            hlast = h;
            h_lds[r][u] = h;
            hs[((size_t)(b0 + r) * S_ + pos) * 256 + dir * 128 + u] = f2bf(h);
        }
        __syncthreads();
    }
    if (tid < 512) {
        int r = tid >> 7, u = tid & 127;
        hfin_base[dir * 65536 + (b0 + r) * 128 + u] = hlast;
        cfin_base[dir * 65536 + (b0 + r) * 128 + u] = c;
    }
}

// ---------------- decoder LSTM only: 10 steps, store hdec[b][t][128] ----------------
__global__ __launch_bounds__(512, 2) void dec_lstm_kernel(
    const int* __restrict__ target,
    const float* __restrict__ xt_d,
    const float* __restrict__ WhhT_d,
    const float* __restrict__ hfin, const float* __restrict__ cfin,
    float* __restrict__ hdec)
{
    const int b0 = blockIdx.x * 2;
    const int tid = threadIdx.x;
    const int j = tid;

    __shared__ __align__(16) float h_lds[2][128];
    __shared__ __align__(16) float g_lds[2][512];

    float4 w4[32];
    #pragma unroll
    for (int kc = 0; kc < 32; ++kc) {
        w4[kc].x = WhhT_d[(kc * 4 + 0) * 512 + j];
        w4[kc].y = WhhT_d[(kc * 4 + 1) * 512 + j];
        w4[kc].z = WhhT_d[(kc * 4 + 2) * 512 + j];
        w4[kc].w = WhhT_d[(kc * 4 + 3) * 512 + j];
    }
    const int r1 = tid >> 7, u1 = tid & 127;
    float c = 0.f;
    if (tid < 256) {
        int b = b0 + r1;
        c = cfin[b * 128 + u1] + cfin[65536 + b * 128 + u1];
        h_lds[r1][u1] = hfin[b * 128 + u1] + hfin[65536 + b * 128 + u1];
    }
    __syncthreads();

    for (int t = 0; t < T_; ++t) {
        int tok0 = (t == 0) ? 0 : target[(b0 + 0) * T_ + t - 1];
        int tok1 = (t == 0) ? 0 : target[(b0 + 1) * T_ + t - 1];
        float a0 = xt_d[tok0 * 512 + j];
        float a1 = xt_d[tok1 * 512 + j];
        #pragma unroll
        for (int kc = 0; kc < 32; ++kc) {
            const float4 w = w4[kc];
            const float4 h0 = *reinterpret_cast<const float4*>(&h_lds[0][kc * 4]);
            const float4 h1 = *reinterpret_cast<const float4*>(&h_lds[1][kc * 4]);
            a0 = fmaf(h0.x, w.x, a0); a0 = fmaf(h0.y, w.y, a0); a0 = fmaf(h0.z, w.z, a0); a0 = fmaf(h0.w, w.w, a0);
            a1 = fmaf(h1.x, w.x, a1); a1 = fmaf(h1.y, w.y, a1); a1 = fmaf(h1.z, w.z, a1); a1 = fmaf(h1.w, w.w, a1);
        }
        g_lds[0][j] = a0; g_lds[1][j] = a1;
        __syncthreads();
        if (tid < 256) {
            float gi = g_lds[r1][u1], gf = g_lds[r1][u1 + 128];
            float gg = g_lds[r1][u1 + 256], go = g_lds[r1][u1 + 384];
            float ii = sigm(gi), ff = sigm(gf), g_ = tanh_(gg), oo = sigm(go);
            c = ff * c + ii * g_;
            float h = oo * tanh_(c);
            h_lds[r1][u1] = h;
            hdec[((size_t)(b0 + r1) * T_ + t) * 128 + u1] = h;
        }
        __syncthreads();
    }
}

// ---------------- attention + output, batched over all 10 t ----------------
__global__ __launch_bounds__(256, 2) void attn_kernel(
    const float* __restrict__ hdec,
    const float* __restrict__ projW, const float* __restrict__ proj_b,
    const float* __restrict__ projWT,
    const float* __restrict__ attn_WT, const float* __restrict__ attn_b,
    const float* __restrict__ out_WT, const float* __restrict__ out_b,
    const ushort_t* __restrict__ hs, float* __restrict__ out)
{
    const int b = blockIdx.x;
    const int tid = threadIdx.x;

    __shared__ __align__(16) float hd[1280];       // hdec[10][128]
    __shared__ __align__(16) float reg1[2560];     // q[10][256] -> ctx[10][128]+comb[10][128]
    __shared__ __align__(16) float sc[2560];       // scores -> aw [10][256]
    __shared__ __align__(16) float part[10240];    // wsum partials [4][10][256]
    __shared__ __align__(16) float wsum[2560];     // [10][256]

    const ushort_t* e = hs + (size_t)b * 65536;

    for (int i = tid; i < 1280; i += 256) hd[i] = hdec[(size_t)b * 1280 + i];
    __syncthreads();

    // phase 0: q[t][d] = sum_k hd[t][k] * projW[k][d]  (swizzle-stored)
    {
        float acc[10];
        #pragma unroll
        for (int t = 0; t < 10; ++t) acc[t] = 0.f;
        for (int k = 0; k < 128; ++k) {
            float pw = projW[k * 256 + tid];
            #pragma unroll
            for (int t = 0; t < 10; ++t) acc[t] = fmaf(hd[t * 128 + k], pw, acc[t]);
        }
        int swd = tid ^ ((((uint_t)tid >> 5) & 7) << 2);
        #pragma unroll
        for (int t = 0; t < 10; ++t) reg1[t * 256 + swd] = acc[t];
    }
    __syncthreads();

    // phase 1: scores[t][s] = e[s][:] . q[t][:]  (8 lanes per s, k8 owns 32 d)
    {
        const int w = tid >> 6, l = tid & 63;
        const int s3 = l >> 3, k8 = l & 7;
        for (int pass = 0; pass < 8; ++pass) {
            int s = w * 64 + pass * 8 + s3;
            const ushort_t* row = e + s * 256 + k8 * 32;
            uint4 e0 = *reinterpret_cast<const uint4*>(row);
            uint4 e1 = *reinterpret_cast<const uint4*>(row + 8);
            uint4 e2 = *reinterpret_cast<const uint4*>(row + 16);
            uint4 e3 = *reinterpret_cast<const uint4*>(row + 24);
            float acc[10];
            #pragma unroll
            for (int t = 0; t < 10; ++t) {
                const float* qb = &reg1[t * 256];
                float a = 0.f;
                #define QCH(i) (*reinterpret_cast<const float4*>(&qb[(k8 * 32 + (i) * 4) ^ (k8 << 2)]))
                #define DOT4(pa, pb, qv) { float4 q_ = (qv); \
                    a = fmaf(bflo(pa), q_.x, a); a = fmaf(bfhi(pa), q_.y, a); \
                    a = fmaf(bflo(pb), q_.z, a); a = fmaf(bfhi(pb), q_.w, a); }
                DOT4(e0.x, e0.y, QCH(0)); DOT4(e0.z, e0.w, QCH(1));
                DOT4(e1.x, e1.y, QCH(2)); DOT4(e1.z, e1.w, QCH(3));
                DOT4(e2.x, e2.y, QCH(4)); DOT4(e2.z, e2.w, QCH(5));
                DOT4(e3.x, e3.y, QCH(6)); DOT4(e3.z, e3.w, QCH(7));
                #undef QCH
                #undef DOT4
                acc[t] = a;
            }
            #pragma unroll
            for (int t = 0; t < 10; ++t) {
                acc[t] += __shfl_xor(acc[t], 1);
                acc[t] += __shfl_xor(acc[t], 2);
                acc[t] += __shfl_xor(acc[t], 4);
            }
            if (k8 == 0) {
                #pragma unroll
                for (int t = 0; t < 10; ++t) sc[t * 256 + s] = acc[t];
            }
        }
    }
    __syncthreads();

    // phase 2: softmax per (t) row over 256 s
    {
        const int w = tid >> 6, l = tid & 63;
        for (int t = w; t < 10; t += 4) {
            float4 sv = *reinterpret_cast<const float4*>(&sc[t * 256 + l * 4]);
            float m = fmaxf(fmaxf(sv.x, sv.y), fmaxf(sv.z, sv.w));
            #pragma unroll
            for (int o = 1; o < 64; o <<= 1) m = fmaxf(m, __shfl_xor(m, o));
            float e0 = fast_exp2((sv.x - m) * 1.4426950408889634f);
            float e1 = fast_exp2((sv.y - m) * 1.4426950408889634f);
            float e2 = fast_exp2((sv.z - m) * 1.4426950408889634f);
            float e3 = fast_exp2((sv.w - m) * 1.4426950408889634f);
            float ssum = e0 + e1 + e2 + e3;
            #pragma unroll
            for (int o = 1; o < 64; o <<= 1) ssum += __shfl_xor(ssum, o);
            float inv = fast_rcp(ssum);
            *reinterpret_cast<float4*>(&sc[t * 256 + l * 4]) =
                make_float4(e0 * inv, e1 * inv, e2 * inv, e3 * inv);
        }
    }
    __syncthreads();

    // phase 3: wsum partials: wave w covers s-quarter, lane owns 4 d, all 10 t
    {
        const int w = tid >> 6, l = tid & 63;
        float ax[10], ay[10], az[10], aw2[10];
        #pragma unroll
        for (int t = 0; t < 10; ++t) { ax[t] = 0.f; ay[t] = 0.f; az[t] = 0.f; aw2[t] = 0.f; }
        const ushort_t* col = e + l * 4;
        for (int s = w * 64; s < w * 64 + 64; ++s) {
            uint2 uu = *reinterpret_cast<const uint2*>(col + (size_t)s * 256);
            float v0 = bflo(uu.x), v1 = bfhi(uu.x), v2 = bflo(uu.y), v3 = bfhi(uu.y);
            #pragma unroll
            for (int t = 0; t < 10; ++t) {
                float awv = sc[t * 256 + s];
                ax[t] = fmaf(v0, awv, ax[t]); ay[t] = fmaf(v1, awv, ay[t]);
                az[t] = fmaf(v2, awv, az[t]); aw2[t] = fmaf(v3, awv, aw2[t]);
            }
        }
        #pragma unroll
        for (int t = 0; t < 10; ++t)
            *reinterpret_cast<float4*>(&part[(w * 10 + t) * 256 + l * 4]) =
                make_float4(ax[t], ay[t], az[t], aw2[t]);
    }
    __syncthreads();

    // phase 4: reduce partials
    for (int i = tid; i < 2560; i += 256)
        wsum[i] = part[i] + part[2560 + i] + part[5120 + i] + part[7680 + i];
    __syncthreads();

    // phase 5: ctx[t][u] = proj_b[u] + sum_k projW[u][k] wsum[t][k]   -> reg1[0..1280)
    {
        const int u = tid & 127, th = tid >> 7;
        float acc[5];
        #pragma unroll
        for (int i = 0; i < 5; ++i) acc[i] = proj_b[u];
        for (int k = 0; k < 256; ++k) {
            float pw = projWT[k * 128 + u];
            #pragma unroll
            for (int i = 0; i < 5; ++i) acc[i] = fmaf(pw, wsum[(th * 5 + i) * 256 + k], acc[i]);
        }
        #pragma unroll
        for (int i = 0; i < 5; ++i) reg1[(th * 5 + i) * 128 + u] = acc[i];
    }
    __syncthreads();

    // phase 6: comb[t][u] = tanh(attn_b[u] + attnW[u][:128].h[t] + attnW[u][128:].ctx[t]) -> reg1[1280..)
    {
        const int u = tid & 127, th = tid >> 7;
        float acc[5];
        #pragma unroll
        for (int i = 0; i < 5; ++i) acc[i] = attn_b[u];
        for (int k = 0; k < 128; ++k) {
            float a1 = attn_WT[k * 128 + u];
            #pragma unroll
            for (int i = 0; i < 5; ++i) acc[i] = fmaf(a1, hd[(th * 5 + i) * 128 + k], acc[i]);
        }
        for (int k = 0; k < 128; ++k) {
            float a2 = attn_WT[(128 + k) * 128 + u];
            #pragma unroll
            for (int i = 0; i < 5; ++i) acc[i] = fmaf(a2, reg1[(th * 5 + i) * 128 + k], acc[i]);
        }
        #pragma unroll
        for (int i = 0; i < 5; ++i) reg1[1280 + (th * 5 + i) * 128 + u] = tanh_(acc[i]);
    }
    __syncthreads();

    // phase 7: logits
    for (int o = tid; o < 280; o += 256) {
        int t = o / 28, v = o - t * 28;
        float acc = out_b[v];
        #pragma unroll 4
        for (int k = 0; k < 128; ++k)
            acc = fmaf(out_WT[k * 28 + v], reg1[1280 + t * 128 + k], acc);
        out[(size_t)b * 280 + o] = acc;
    }
}

extern "C" void kernel_launch(void* const* d_in, const int* in_sizes, int n_in,
                              void* d_out, int out_size, void* d_ws, size_t ws_size,
                              hipStream_t stream) {
    const int* src      = (const int*)d_in[0];
    const int* target   = (const int*)d_in[1];
    const float* embed  = (const float*)d_in[2];
    const float* Wih_f  = (const float*)d_in[3];
    const float* Whh_f  = (const float*)d_in[4];
    const float* b_f    = (const float*)d_in[5];
    const float* Wih_b  = (const float*)d_in[6];
    const float* Whh_b  = (const float*)d_in[7];
    const float* b_b    = (const float*)d_in[8];
    const float* Wih_d  = (const float*)d_in[9];
    const float* Whh_d  = (const float*)d_in[10];
    const float* b_d    = (const float*)d_in[11];
    const float* proj_W = (const float*)d_in[12];
    const float* proj_b = (const float*)d_in[13];
    const float* attn_W = (const float*)d_in[14];
    const float* attn_b = (const float*)d_in[15];
    const float* out_W  = (const float*)d_in[16];
    const float* out_b  = (const float*)d_in[17];

    float* ws = (float*)d_ws;
    ushort_t* hs = (ushort_t*)((char*)d_ws + HS_BYTE_OFF);
    float* out = (float*)d_out;

    prep_kernel<<<PREP_N / 256, 256, 0, stream>>>(
        embed, Wih_f, b_f, Wih_b, b_b, Wih_d, b_d,
        Whh_f, Whh_b, Whh_d, attn_W, out_W, proj_W, ws);

    enc_kernel<<<dim3(128, 2), 1024, 0, stream>>>(
        src, ws + XT_F, ws + WT_F, ws + HFIN, ws + CFIN, hs);

    dec_lstm_kernel<<<256, 512, 0, stream>>>(
        target, ws + XT_D, ws + WT_D, ws + HFIN, ws + CFIN, ws + HDEC);

    attn_kernel<<<512, 256, 0, stream>>>(
        ws + HDEC, proj_W, proj_b, ws + PWT, ws + AWT, attn_b,
        ws + OWT, out_b, hs, out);
}

// Round 4
// 556.147 us; speedup vs baseline: 1.4755x; 1.4755x over previous
//
#include <hip/hip_runtime.h>
#include <hip/hip_bf16.h>
#include <stdint.h>

typedef unsigned short ushort_t;
typedef unsigned int uint_t;
typedef __attribute__((ext_vector_type(8))) short bfrag;   // 8 bf16 = 4 VGPR
typedef __attribute__((ext_vector_type(4))) float f32x4;

#define B_ 512
#define S_ 256
#define T_ 10
#define V_ 28
#define H_ 128

// ---- workspace layout (float element offsets) ----
#define XTD 0         // dec xg table [28][512]
#define XTG 14336     // enc xg gate-interleaved [2][28][128][4]
#define WTD 43008     // dec WhhT [128][512]
#define AWT 108544    // attn_WT [256][128]
#define OWT 141312    // out_WT [128][28]
#define PWT 144896    // projWT [256][128]
#define WPK 177664    // enc W bf16x2 frag-packed, 262144 ushort (=131072 float slots)
#define HFIN 308736
#define CFIN 439808
#define HDEC 570880
#define HS_BYTE_OFF (1226240ull * 4ull)
#define PREP_N 439808

__device__ __forceinline__ float fast_exp2(float x) { return __builtin_amdgcn_exp2f(x); }
__device__ __forceinline__ float fast_rcp(float x)  { return __builtin_amdgcn_rcpf(x); }
__device__ __forceinline__ float sigm(float x) {
    return fast_rcp(1.f + fast_exp2(-1.4426950408889634f * x));
}
__device__ __forceinline__ float tanh_(float x) {
    return 1.f - 2.f * fast_rcp(1.f + fast_exp2(2.8853900817779268f * x));
}
__device__ __forceinline__ ushort_t f2bf(float x) {
    uint_t u = __float_as_uint(x);
    return (ushort_t)((u + 0x7FFFu + ((u >> 16) & 1u)) >> 16);  // RNE
}
__device__ __forceinline__ float bflo(uint_t u) { return __uint_as_float(u << 16); }
__device__ __forceinline__ float bfhi(uint_t u) { return __uint_as_float(u & 0xFFFF0000u); }

// ---------------- prep ----------------
__global__ __launch_bounds__(256) void prep_kernel(
    const float* __restrict__ embed,
    const float* __restrict__ Wih_f, const float* __restrict__ b_f,
    const float* __restrict__ Wih_b, const float* __restrict__ b_b,
    const float* __restrict__ Wih_d, const float* __restrict__ b_d,
    const float* __restrict__ Whh_f, const float* __restrict__ Whh_b,
    const float* __restrict__ Whh_d,
    const float* __restrict__ attn_W, const float* __restrict__ out_W,
    const float* __restrict__ proj_W,
    float* __restrict__ ws)
{
    int i = blockIdx.x * 256 + threadIdx.x;
    if (i < XTG) {                         // dec xg table: [v][j]
        int v = i >> 9, jj = i & 511;
        float acc = b_d[jj];
        #pragma unroll
        for (int e = 0; e < 32; ++e) acc = fmaf(embed[v * 32 + e], Wih_d[jj * 32 + e], acc);
        ws[XTD + i] = acc;
    } else if (i < WTD) {                  // enc xg gate-interleaved: [d][v][u][g]
        int r = i - XTG; int d = r / 14336; int rem = r % 14336;
        int v = rem >> 9, q = rem & 511;
        int uu = q >> 2, g = q & 3;
        int jj = g * 128 + uu;
        const float* Wih = d ? Wih_b : Wih_f;
        const float* bb  = d ? b_b   : b_f;
        float acc = bb[jj];
        #pragma unroll
        for (int e = 0; e < 32; ++e) acc = fmaf(embed[v * 32 + e], Wih[jj * 32 + e], acc);
        ws[XTG + r] = acc;
    } else if (i < AWT) {                  // dec WhhT[k][j]
        int r = i - WTD; int k = r >> 9, jj = r & 511;
        ws[WTD + r] = Whh_d[jj * 128 + k];
    } else if (i < OWT) {                  // attn_WT[k][u]
        int r = i - AWT; int k = r >> 7, uu = r & 127;
        ws[i] = attn_W[uu * 256 + k];
    } else if (i < PWT) {                  // out_WT[k][v]
        int r = i - OWT; int k = r / 28, v = r % 28;
        ws[i] = out_W[v * 128 + k];
    } else if (i < WPK) {                  // projWT[k][u]
        int r = i - PWT; int k = r >> 7, uu = r & 127;
        ws[i] = proj_W[uu * 256 + k];
    } else if (i < PREP_N) {               // enc weight frag pack (bf16 hi/lo)
        int i2 = i - WPK;
        int e  = i2 & 7;
        int ll = (i2 >> 3) & 63;
        int p  = (i2 >> 9) & 1;
        int kt = (i2 >> 10) & 3;
        int ni = (i2 >> 12) & 3;
        int wv = (i2 >> 14) & 7;
        int d  = (i2 >> 17) & 1;
        int jj = (ni * 8 + wv) * 16 + (ll & 15);   // gate column (N)
        int k  = kt * 32 + (ll >> 4) * 8 + e;      // K index
        const float* Whh = d ? Whh_b : Whh_f;
        float Wv = Whh[jj * 128 + k];
        ushort_t hi = f2bf(Wv);
        ushort_t ov = p ? f2bf(Wv - __uint_as_float((uint_t)hi << 16)) : hi;
        ((ushort_t*)(ws + WPK))[i2] = ov;
    }
}

// ---------------- encoder: MFMA, 16 rows/block, 64 blocks, 8 waves ----------------
// wave w owns N-tiles {w, w+8, w+16, w+24} = gates (i,f,g,o) for u in [16w,16w+16)
// bf16x3 split: g = h_hi*W_hi + h_hi*W_lo + h_lo*W_hi  (fp32 acc)
__global__ __launch_bounds__(512, 2) void enc_kernel(
    const int* __restrict__ src,
    const float* __restrict__ xtg_base,     // ws+XTG
    const ushort_t* __restrict__ wpk,       // ws+WPK
    float* __restrict__ hfin, float* __restrict__ cfin,
    ushort_t* __restrict__ hs)
{
    const int bx = blockIdx.x;
    const int dir = bx >> 5;
    const int b0 = (bx & 31) << 4;
    const int tid = threadIdx.x;
    const int w = tid >> 6, l = tid & 63;
    const int lg = l >> 4, col = l & 15;
    const int u = (w << 4) + col;

    __shared__ ushort_t hA[2][2][2048];   // [buf][hi/lo][row*128 + swizzled k]
    __shared__ int tokl[256][16];         // [s][row]

    for (int i = tid; i < 4096; i += 512) {
        int row = i >> 8, s = i & 255;
        tokl[s][row] = src[(b0 + row) * S_ + s];
    }
    {   // zero h buffer 0 (hi+lo)
        uint_t* z = (uint_t*)&hA[0][0][0];
        for (int i = tid; i < 2048; i += 512) z[i] = 0u;
    }

    const float* xtg = xtg_base + dir * 14336;

    // persistent B fragments: 4 N-tiles x 4 K-tiles x {hi,lo} = 128 VGPR
    bfrag bh[4][4], bl[4][4];
    {
        const ushort_t* wb = wpk + (((size_t)dir * 8 + w) << 14) + l * 8;
        #pragma unroll
        for (int ni = 0; ni < 4; ++ni)
            #pragma unroll
            for (int kt = 0; kt < 4; ++kt) {
                bh[ni][kt] = *reinterpret_cast<const bfrag*>(wb + (((ni * 4 + kt) * 2 + 0) << 9));
                bl[ni][kt] = *reinterpret_cast<const bfrag*>(wb + (((ni * 4 + kt) * 2 + 1) << 9));
            }
    }
    __syncthreads();

    float cs0 = 0.f, cs1 = 0.f, cs2 = 0.f, cs3 = 0.f;
    float hl0 = 0.f, hl1 = 0.f, hl2 = 0.f, hl3 = 0.f;
    f32x4 xg0, xg1, xg2, xg3;
    {
        int p0 = dir ? (S_ - 1) : 0;
        int r0 = lg << 2;
        xg0 = *reinterpret_cast<const f32x4*>(xtg + ((size_t)tokl[p0][r0 + 0] << 9) + (u << 2));
        xg1 = *reinterpret_cast<const f32x4*>(xtg + ((size_t)tokl[p0][r0 + 1] << 9) + (u << 2));
        xg2 = *reinterpret_cast<const f32x4*>(xtg + ((size_t)tokl[p0][r0 + 2] << 9) + (u << 2));
        xg3 = *reinterpret_cast<const f32x4*>(xtg + ((size_t)tokl[p0][r0 + 3] << 9) + (u << 2));
    }

    const int arow = col;                 // A-fragment row = lane&15
    const int sw = (arow & 7) << 3;       // XOR swizzle (ushort units)
    const int abase = arow * 128;

    for (int t = 0; t < S_; ++t) {
        const int cb = t & 1, nb = cb ^ 1;
        const int pos = dir ? (S_ - 1 - t) : t;

        // acc init = xg (i,f,g,o per row)
        f32x4 acc0 = {xg0[0], xg1[0], xg2[0], xg3[0]};
        f32x4 acc1 = {xg0[1], xg1[1], xg2[1], xg3[1]};
        f32x4 acc2 = {xg0[2], xg1[2], xg2[2], xg3[2]};
        f32x4 acc3 = {xg0[3], xg1[3], xg2[3], xg3[3]};

        const ushort_t* hb_hi = &hA[cb][0][0];
        const ushort_t* hb_lo = &hA[cb][1][0];
        #define KT(kt) { \
            int ai = abase + ((((kt) << 5) + (lg << 3)) ^ sw); \
            bfrag ah = *reinterpret_cast<const bfrag*>(hb_hi + ai); \
            bfrag al = *reinterpret_cast<const bfrag*>(hb_lo + ai); \
            acc0 = __builtin_amdgcn_mfma_f32_16x16x32_bf16(ah, bh[0][kt], acc0, 0, 0, 0); \
            acc1 = __builtin_amdgcn_mfma_f32_16x16x32_bf16(ah, bh[1][kt], acc1, 0, 0, 0); \
            acc2 = __builtin_amdgcn_mfma_f32_16x16x32_bf16(ah, bh[2][kt], acc2, 0, 0, 0); \
            acc3 = __builtin_amdgcn_mfma_f32_16x16x32_bf16(ah, bh[3][kt], acc3, 0, 0, 0); \
            acc0 = __builtin_amdgcn_mfma_f32_16x16x32_bf16(ah, bl[0][kt], acc0, 0, 0, 0); \
            acc1 = __builtin_amdgcn_mfma_f32_16x16x32_bf16(ah, bl[1][kt], acc1, 0, 0, 0); \
            acc2 = __builtin_amdgcn_mfma_f32_16x16x32_bf16(ah, bl[2][kt], acc2, 0, 0, 0); \
            acc3 = __builtin_amdgcn_mfma_f32_16x16x32_bf16(ah, bl[3][kt], acc3, 0, 0, 0); \
            acc0 = __builtin_amdgcn_mfma_f32_16x16x32_bf16(al, bh[0][kt], acc0, 0, 0, 0); \
            acc1 = __builtin_amdgcn_mfma_f32_16x16x32_bf16(al, bh[1][kt], acc1, 0, 0, 0); \
            acc2 = __builtin_amdgcn_mfma_f32_16x16x32_bf16(al, bh[2][kt], acc2, 0, 0, 0); \
            acc3 = __builtin_amdgcn_mfma_f32_16x16x32_bf16(al, bh[3][kt], acc3, 0, 0, 0); \
        }
        KT(0) KT(1) KT(2) KT(3)
        #undef KT

        // prefetch next step's xg (hidden under cell)
        if (t + 1 < S_) {
            int pn = dir ? (S_ - 2 - t) : (t + 1);
            int r0 = lg << 2;
            xg0 = *reinterpret_cast<const f32x4*>(xtg + ((size_t)tokl[pn][r0 + 0] << 9) + (u << 2));
            xg1 = *reinterpret_cast<const f32x4*>(xtg + ((size_t)tokl[pn][r0 + 1] << 9) + (u << 2));
            xg2 = *reinterpret_cast<const f32x4*>(xtg + ((size_t)tokl[pn][r0 + 2] << 9) + (u << 2));
            xg3 = *reinterpret_cast<const f32x4*>(xtg + ((size_t)tokl[pn][r0 + 3] << 9) + (u << 2));
        }

        #define CELL(r, CSV, HLV) { \
            float gi = acc0[r], gf = acc1[r], gg = acc2[r], go = acc3[r]; \
            float ii = sigm(gi), ff = sigm(gf), gG = tanh_(gg), oo = sigm(go); \
            CSV = ff * CSV + ii * gG; \
            float h = oo * tanh_(CSV); \
            HLV = h; \
            int row = (lg << 2) + (r); \
            ushort_t hi = f2bf(h); \
            ushort_t lo = f2bf(h - __uint_as_float((uint_t)hi << 16)); \
            int wi = row * 128 + (u ^ ((row & 7) << 3)); \
            hA[nb][0][wi] = hi; hA[nb][1][wi] = lo; \
            hs[((size_t)(b0 + row) * S_ + pos) * 256 + dir * 128 + u] = hi; \
        }
        CELL(0, cs0, hl0) CELL(1, cs1, hl1) CELL(2, cs2, hl2) CELL(3, cs3, hl3)
        #undef CELL

        __syncthreads();
    }

    #define FIN(r, CSV, HLV) { \
        int row = (lg << 2) + (r); \
        hfin[dir * 65536 + (b0 + row) * 128 + u] = HLV; \
        cfin[dir * 65536 + (b0 + row) * 128 + u] = CSV; }
    FIN(0, cs0, hl0) FIN(1, cs1, hl1) FIN(2, cs2, hl2) FIN(3, cs3, hl3)
    #undef FIN
}

// ---------------- decoder LSTM only: 10 steps, store hdec[b][t][128] ----------------
__global__ __launch_bounds__(512, 2) void dec_lstm_kernel(
    const int* __restrict__ target,
    const float* __restrict__ xt_d,
    const float* __restrict__ WhhT_d,
    const float* __restrict__ hfin, const float* __restrict__ cfin,
    float* __restrict__ hdec)
{
    const int b0 = blockIdx.x * 2;
    const int tid = threadIdx.x;
    const int j = tid;

    __shared__ __align__(16) float h_lds[2][128];
    __shared__ __align__(16) float g_lds[2][512];

    float4 w4[32];
    #pragma unroll
    for (int kc = 0; kc < 32; ++kc) {
        w4[kc].x = WhhT_d[(kc * 4 + 0) * 512 + j];
        w4[kc].y = WhhT_d[(kc * 4 + 1) * 512 + j];
        w4[kc].z = WhhT_d[(kc * 4 + 2) * 512 + j];
        w4[kc].w = WhhT_d[(kc * 4 + 3) * 512 + j];
    }
    const int r1 = tid >> 7, u1 = tid & 127;
    float c = 0.f;
    if (tid < 256) {
        int b = b0 + r1;
        c = cfin[b * 128 + u1] + cfin[65536 + b * 128 + u1];
        h_lds[r1][u1] = hfin[b * 128 + u1] + hfin[65536 + b * 128 + u1];
    }
    __syncthreads();

    for (int t = 0; t < T_; ++t) {
        int tok0 = (t == 0) ? 0 : target[(b0 + 0) * T_ + t - 1];
        int tok1 = (t == 0) ? 0 : target[(b0 + 1) * T_ + t - 1];
        float a0 = xt_d[tok0 * 512 + j];
        float a1 = xt_d[tok1 * 512 + j];
        #pragma unroll
        for (int kc = 0; kc < 32; ++kc) {
            const float4 w = w4[kc];
            const float4 h0 = *reinterpret_cast<const float4*>(&h_lds[0][kc * 4]);
            const float4 h1 = *reinterpret_cast<const float4*>(&h_lds[1][kc * 4]);
            a0 = fmaf(h0.x, w.x, a0); a0 = fmaf(h0.y, w.y, a0); a0 = fmaf(h0.z, w.z, a0); a0 = fmaf(h0.w, w.w, a0);
            a1 = fmaf(h1.x, w.x, a1); a1 = fmaf(h1.y, w.y, a1); a1 = fmaf(h1.z, w.z, a1); a1 = fmaf(h1.w, w.w, a1);
        }
        g_lds[0][j] = a0; g_lds[1][j] = a1;
        __syncthreads();
        if (tid < 256) {
            float gi = g_lds[r1][u1], gf = g_lds[r1][u1 + 128];
            float gg = g_lds[r1][u1 + 256], go = g_lds[r1][u1 + 384];
            float ii = sigm(gi), ff = sigm(gf), g_ = tanh_(gg), oo = sigm(go);
            c = ff * c + ii * g_;
            float h = oo * tanh_(c);
            h_lds[r1][u1] = h;
            hdec[((size_t)(b0 + r1) * T_ + t) * 128 + u1] = h;
        }
        __syncthreads();
    }
}

// ---------------- attention + output, batched over all 10 t ----------------
__global__ __launch_bounds__(256, 2) void attn_kernel(
    const float* __restrict__ hdec,
    const float* __restrict__ projW, const float* __restrict__ proj_b,
    const float* __restrict__ projWT,
    const float* __restrict__ attn_WT, const float* __restrict__ attn_b,
    const float* __restrict__ out_WT, const float* __restrict__ out_b,
    const ushort_t* __restrict__ hs, float* __restrict__ out)
{
    const int b = blockIdx.x;
    const int tid = threadIdx.x;

    __shared__ __align__(16) float hd[1280];
    __shared__ __align__(16) float reg1[2560];
    __shared__ __align__(16) float sc[2560];
    __shared__ __align__(16) float part[10240];
    __shared__ __align__(16) float wsum[2560];

    const ushort_t* e = hs + (size_t)b * 65536;

    for (int i = tid; i < 1280; i += 256) hd[i] = hdec[(size_t)b * 1280 + i];
    __syncthreads();

    // phase 0: q[t][d] = sum_k hd[t][k] * projW[k][d]  (swizzle-stored)
    {
        float acc[10];
        #pragma unroll
        for (int t = 0; t < 10; ++t) acc[t] = 0.f;
        for (int k = 0; k < 128; ++k) {
            float pw = projW[k * 256 + tid];
            #pragma unroll
            for (int t = 0; t < 10; ++t) acc[t] = fmaf(hd[t * 128 + k], pw, acc[t]);
        }
        int swd = tid ^ ((((uint_t)tid >> 5) & 7) << 2);
        #pragma unroll
        for (int t = 0; t < 10; ++t) reg1[t * 256 + swd] = acc[t];
    }
    __syncthreads();

    // phase 1: scores[t][s] = e[s][:] . q[t][:]
    {
        const int w = tid >> 6, l = tid & 63;
        const int s3 = l >> 3, k8 = l & 7;
        for (int pass = 0; pass < 8; ++pass) {
            int s = w * 64 + pass * 8 + s3;
            const ushort_t* row = e + s * 256 + k8 * 32;
            uint4 e0 = *reinterpret_cast<const uint4*>(row);
            uint4 e1 = *reinterpret_cast<const uint4*>(row + 8);
            uint4 e2 = *reinterpret_cast<const uint4*>(row + 16);
            uint4 e3 = *reinterpret_cast<const uint4*>(row + 24);
            float acc[10];
            #pragma unroll
            for (int t = 0; t < 10; ++t) {
                const float* qb = &reg1[t * 256];
                float a = 0.f;
                #define QCH(i) (*reinterpret_cast<const float4*>(&qb[(k8 * 32 + (i) * 4) ^ (k8 << 2)]))
                #define DOT4(pa, pb, qv) { float4 q_ = (qv); \
                    a = fmaf(bflo(pa), q_.x, a); a = fmaf(bfhi(pa), q_.y, a); \
                    a = fmaf(bflo(pb), q_.z, a); a = fmaf(bfhi(pb), q_.w, a); }
                DOT4(e0.x, e0.y, QCH(0)); DOT4(e0.z, e0.w, QCH(1));
                DOT4(e1.x, e1.y, QCH(2)); DOT4(e1.z, e1.w, QCH(3));
                DOT4(e2.x, e2.y, QCH(4)); DOT4(e2.z, e2.w, QCH(5));
                DOT4(e3.x, e3.y, QCH(6)); DOT4(e3.z, e3.w, QCH(7));
                #undef QCH
                #undef DOT4
                acc[t] = a;
            }
            #pragma unroll
            for (int t = 0; t < 10; ++t) {
                acc[t] += __shfl_xor(acc[t], 1);
                acc[t] += __shfl_xor(acc[t], 2);
                acc[t] += __shfl_xor(acc[t], 4);
            }
            if (k8 == 0) {
                #pragma unroll
                for (int t = 0; t < 10; ++t) sc[t * 256 + s] = acc[t];
            }
        }
    }
    __syncthreads();

    // phase 2: softmax
    {
        const int w = tid >> 6, l = tid & 63;
        for (int t = w; t < 10; t += 4) {
            float4 sv = *reinterpret_cast<const float4*>(&sc[t * 256 + l * 4]);
            float m = fmaxf(fmaxf(sv.x, sv.y), fmaxf(sv.z, sv.w));
            #pragma unroll
            for (int o = 1; o < 64; o <<= 1) m = fmaxf(m, __shfl_xor(m, o));
            float e0 = fast_exp2((sv.x - m) * 1.4426950408889634f);
            float e1 = fast_exp2((sv.y - m) * 1.4426950408889634f);
            float e2 = fast_exp2((sv.z - m) * 1.4426950408889634f);
            float e3 = fast_exp2((sv.w - m) * 1.4426950408889634f);
            float ssum = e0 + e1 + e2 + e3;
            #pragma unroll
            for (int o = 1; o < 64; o <<= 1) ssum += __shfl_xor(ssum, o);
            float inv = fast_rcp(ssum);
            *reinterpret_cast<float4*>(&sc[t * 256 + l * 4]) =
                make_float4(e0 * inv, e1 * inv, e2 * inv, e3 * inv);
        }
    }
    __syncthreads();

    // phase 3: wsum partials
    {
        const int w = tid >> 6, l = tid & 63;
        float ax[10], ay[10], az[10], aw2[10];
        #pragma unroll
        for (int t = 0; t < 10; ++t) { ax[t] = 0.f; ay[t] = 0.f; az[t] = 0.f; aw2[t] = 0.f; }
        const ushort_t* col = e + l * 4;
        for (int s = w * 64; s < w * 64 + 64; ++s) {
            uint2 uu = *reinterpret_cast<const uint2*>(col + (size_t)s * 256);
            float v0 = bflo(uu.x), v1 = bfhi(uu.x), v2 = bflo(uu.y), v3 = bfhi(uu.y);
            #pragma unroll
            for (int t = 0; t < 10; ++t) {
                float awv = sc[t * 256 + s];
                ax[t] = fmaf(v0, awv, ax[t]); ay[t] = fmaf(v1, awv, ay[t]);
                az[t] = fmaf(v2, awv, az[t]); aw2[t] = fmaf(v3, awv, aw2[t]);
            }
        }
        #pragma unroll
        for (int t = 0; t < 10; ++t)
            *reinterpret_cast<float4*>(&part[(w * 10 + t) * 256 + l * 4]) =
                make_float4(ax[t], ay[t], az[t], aw2[t]);
    }
    __syncthreads();

    // phase 4: reduce partials
    for (int i = tid; i < 2560; i += 256)
        wsum[i] = part[i] + part[2560 + i] + part[5120 + i] + part[7680 + i];
    __syncthreads();

    // phase 5: ctx
    {
        const int u = tid & 127, th = tid >> 7;
        float acc[5];
        #pragma unroll
        for (int i = 0; i < 5; ++i) acc[i] = proj_b[u];
        for (int k = 0; k < 256; ++k) {
            float pw = projWT[k * 128 + u];
            #pragma unroll
            for (int i = 0; i < 5; ++i) acc[i] = fmaf(pw, wsum[(th * 5 + i) * 256 + k], acc[i]);
        }
        #pragma unroll
        for (int i = 0; i < 5; ++i) reg1[(th * 5 + i) * 128 + u] = acc[i];
    }
    __syncthreads();

    // phase 6: comb
    {
        const int u = tid & 127, th = tid >> 7;
        float acc[5];
        #pragma unroll
        for (int i = 0; i < 5; ++i) acc[i] = attn_b[u];
        for (int k = 0; k < 128; ++k) {
            float a1 = attn_WT[k * 128 + u];
            #pragma unroll
            for (int i = 0; i < 5; ++i) acc[i] = fmaf(a1, hd[(th * 5 + i) * 128 + k], acc[i]);
        }
        for (int k = 0; k < 128; ++k) {
            float a2 = attn_WT[(128 + k) * 128 + u];
            #pragma unroll
            for (int i = 0; i < 5; ++i) acc[i] = fmaf(a2, reg1[(th * 5 + i) * 128 + k], acc[i]);
        }
        #pragma unroll
        for (int i = 0; i < 5; ++i) reg1[1280 + (th * 5 + i) * 128 + u] = tanh_(acc[i]);
    }
    __syncthreads();

    // phase 7: logits
    for (int o = tid; o < 280; o += 256) {
        int t = o / 28, v = o - t * 28;
        float acc = out_b[v];
        #pragma unroll 4
        for (int k = 0; k < 128; ++k)
            acc = fmaf(out_WT[k * 28 + v], reg1[1280 + t * 128 + k], acc);
        out[(size_t)b * 280 + o] = acc;
    }
}

extern "C" void kernel_launch(void* const* d_in, const int* in_sizes, int n_in,
                              void* d_out, int out_size, void* d_ws, size_t ws_size,
                              hipStream_t stream) {
    const int* src      = (const int*)d_in[0];
    const int* target   = (const int*)d_in[1];
    const float* embed  = (const float*)d_in[2];
    const float* Wih_f  = (const float*)d_in[3];
    const float* Whh_f  = (const float*)d_in[4];
    const float* b_f    = (const float*)d_in[5];
    const float* Wih_b  = (const float*)d_in[6];
    const float* Whh_b  = (const float*)d_in[7];
    const float* b_b    = (const float*)d_in[8];
    const float* Wih_d  = (const float*)d_in[9];
    const float* Whh_d  = (const float*)d_in[10];
    const float* b_d    = (const float*)d_in[11];
    const float* proj_W = (const float*)d_in[12];
    const float* proj_b = (const float*)d_in[13];
    const float* attn_W = (const float*)d_in[14];
    const float* attn_b = (const float*)d_in[15];
    const float* out_W  = (const float*)d_in[16];
    const float* out_b  = (const float*)d_in[17];

    float* ws = (float*)d_ws;
    ushort_t* hs = (ushort_t*)((char*)d_ws + HS_BYTE_OFF);
    float* out = (float*)d_out;

    prep_kernel<<<(PREP_N + 255) / 256, 256, 0, stream>>>(
        embed, Wih_f, b_f, Wih_b, b_b, Wih_d, b_d,
        Whh_f, Whh_b, Whh_d, attn_W, out_W, proj_W, ws);

    enc_kernel<<<64, 512, 0, stream>>>(
        src, ws + XTG, (const ushort_t*)(ws + WPK),
        ws + HFIN, ws + CFIN, hs);

    dec_lstm_kernel<<<256, 512, 0, stream>>>(
        target, ws + XTD, ws + WTD, ws + HFIN, ws + CFIN, ws + HDEC);

    attn_kernel<<<512, 256, 0, stream>>>(
        ws + HDEC, proj_W, proj_b, ws + PWT, ws + AWT, attn_b,
        ws + OWT, out_b, hs, out);
}

// Round 5
// 543.995 us; speedup vs baseline: 1.5084x; 1.0223x over previous
//
#include <hip/hip_runtime.h>
#include <hip/hip_bf16.h>
#include <stdint.h>

typedef unsigned short ushort_t;
typedef unsigned int uint_t;
typedef __attribute__((ext_vector_type(8))) short bfrag;   // 8 bf16 = 4 VGPR
typedef __attribute__((ext_vector_type(4))) float f32x4;

#define B_ 512
#define S_ 256
#define T_ 10
#define V_ 28
#define H_ 128

// ---- workspace layout (float element offsets) ----
#define XTD 0         // dec xg table [28][512]
#define XTG 14336     // enc xg gate-interleaved [2][28][128][4]
#define WTD 43008     // dec WhhT [128][512]
#define AWT 108544    // attn_WT [256][128]
#define OWT 141312    // out_WT [128][28]
#define PWT 144896    // projWT [256][128]
#define WPK 177664    // enc W bf16x2 frag-packed, 262144 ushort (=131072 float slots)
#define HFIN 308736
#define CFIN 439808
#define HDEC 570880
#define HS_BYTE_OFF (1226240ull * 4ull)
#define PREP_N 439808

__device__ __forceinline__ float fast_exp2(float x) { return __builtin_amdgcn_exp2f(x); }
__device__ __forceinline__ float fast_rcp(float x)  { return __builtin_amdgcn_rcpf(x); }
__device__ __forceinline__ float sigm(float x) {
    return fast_rcp(1.f + fast_exp2(-1.4426950408889634f * x));
}
__device__ __forceinline__ float tanh_(float x) {
    return 1.f - 2.f * fast_rcp(1.f + fast_exp2(2.8853900817779268f * x));
}
__device__ __forceinline__ ushort_t f2bf(float x) {
    uint_t u = __float_as_uint(x);
    return (ushort_t)((u + 0x7FFFu + ((u >> 16) & 1u)) >> 16);  // RNE
}
__device__ __forceinline__ float bflo(uint_t u) { return __uint_as_float(u << 16); }
__device__ __forceinline__ float bfhi(uint_t u) { return __uint_as_float(u & 0xFFFF0000u); }

// ---------------- prep ----------------
__global__ __launch_bounds__(256) void prep_kernel(
    const float* __restrict__ embed,
    const float* __restrict__ Wih_f, const float* __restrict__ b_f,
    const float* __restrict__ Wih_b, const float* __restrict__ b_b,
    const float* __restrict__ Wih_d, const float* __restrict__ b_d,
    const float* __restrict__ Whh_f, const float* __restrict__ Whh_b,
    const float* __restrict__ Whh_d,
    const float* __restrict__ attn_W, const float* __restrict__ out_W,
    const float* __restrict__ proj_W,
    float* __restrict__ ws)
{
    int i = blockIdx.x * 256 + threadIdx.x;
    if (i < XTG) {                         // dec xg table: [v][j]
        int v = i >> 9, jj = i & 511;
        float acc = b_d[jj];
        #pragma unroll
        for (int e = 0; e < 32; ++e) acc = fmaf(embed[v * 32 + e], Wih_d[jj * 32 + e], acc);
        ws[XTD + i] = acc;
    } else if (i < WTD) {                  // enc xg gate-interleaved: [d][v][u][g]
        int r = i - XTG; int d = r / 14336; int rem = r % 14336;
        int v = rem >> 9, q = rem & 511;
        int uu = q >> 2, g = q & 3;
        int jj = g * 128 + uu;
        const float* Wih = d ? Wih_b : Wih_f;
        const float* bb  = d ? b_b   : b_f;
        float acc = bb[jj];
        #pragma unroll
        for (int e = 0; e < 32; ++e) acc = fmaf(embed[v * 32 + e], Wih[jj * 32 + e], acc);
        ws[XTG + r] = acc;
    } else if (i < AWT) {                  // dec WhhT[k][j]
        int r = i - WTD; int k = r >> 9, jj = r & 511;
        ws[WTD + r] = Whh_d[jj * 128 + k];
    } else if (i < OWT) {                  // attn_WT[k][u]
        int r = i - AWT; int k = r >> 7, uu = r & 127;
        ws[i] = attn_W[uu * 256 + k];
    } else if (i < PWT) {                  // out_WT[k][v]
        int r = i - OWT; int k = r / 28, v = r % 28;
        ws[i] = out_W[v * 128 + k];
    } else if (i < WPK) {                  // projWT[k][u]
        int r = i - PWT; int k = r >> 7, uu = r & 127;
        ws[i] = proj_W[uu * 256 + k];
    } else if (i < PREP_N) {               // enc weight frag pack (bf16 hi/lo)
        int i2 = i - WPK;
        int e  = i2 & 7;
        int ll = (i2 >> 3) & 63;
        int p  = (i2 >> 9) & 1;
        int kt = (i2 >> 10) & 3;
        int ni = (i2 >> 12) & 3;
        int wv = (i2 >> 14) & 7;
        int d  = (i2 >> 17) & 1;
        int jj = (ni * 8 + wv) * 16 + (ll & 15);   // gate column (N)
        int k  = kt * 32 + (ll >> 4) * 8 + e;      // K index
        const float* Whh = d ? Whh_b : Whh_f;
        float Wv = Whh[jj * 128 + k];
        ushort_t hi = f2bf(Wv);
        ushort_t ov = p ? f2bf(Wv - __uint_as_float((uint_t)hi << 16)) : hi;
        ((ushort_t*)(ws + WPK))[i2] = ov;
    }
}

// ---------------- encoder: MFMA, 16 rows/block, 64 blocks, 8 waves ----------------
// wave w owns N-tiles {w, w+8, w+16, w+24} = gates (i,f,g,o) for u in [16w,16w+16)
// bf16x3 split: g = h_hi*W_hi + h_hi*W_lo + h_lo*W_hi  (fp32 acc)
// Per-step: coalesced flush of h_{t-1} + early xg prefetch so the barrier's
// vmcnt(0) drain is free (stores/loads issued ~1000cyc before s_barrier).
__global__ __launch_bounds__(512, 2) void enc_kernel(
    const int* __restrict__ src,
    const float* __restrict__ xtg_base,     // ws+XTG
    const ushort_t* __restrict__ wpk,       // ws+WPK
    float* __restrict__ hfin, float* __restrict__ cfin,
    ushort_t* __restrict__ hs)
{
    const int bx = blockIdx.x;
    const int dir = bx >> 5;
    const int b0 = (bx & 31) << 4;
    const int tid = threadIdx.x;
    const int w = tid >> 6, l = tid & 63;
    const int lg = l >> 4, col = l & 15;
    const int u = (w << 4) + col;

    __shared__ ushort_t hA[2][2][2048];   // [buf][hi/lo][row*128 + swizzled u]
    __shared__ int tokl[256][16];         // [s][row]

    for (int i = tid; i < 4096; i += 512) {
        int row = i >> 8, s = i & 255;
        tokl[s][row] = src[(b0 + row) * S_ + s];
    }
    {   // zero h buffer 0 (hi+lo planes)
        uint_t* z = (uint_t*)&hA[0][0][0];
        for (int i = tid; i < 2048; i += 512) z[i] = 0u;
    }

    const float* xtg = xtg_base + dir * 14336;

    // persistent B fragments: 4 N-tiles x 4 K-tiles x {hi,lo} = 128 regs (VGPR/AGPR)
    bfrag bh[4][4], bl[4][4];
    {
        const ushort_t* wb = wpk + (((size_t)dir * 8 + w) << 14) + l * 8;
        #pragma unroll
        for (int ni = 0; ni < 4; ++ni)
            #pragma unroll
            for (int kt = 0; kt < 4; ++kt) {
                bh[ni][kt] = *reinterpret_cast<const bfrag*>(wb + (((ni * 4 + kt) * 2 + 0) << 9));
                bl[ni][kt] = *reinterpret_cast<const bfrag*>(wb + (((ni * 4 + kt) * 2 + 1) << 9));
            }
    }
    __syncthreads();

    float cs0 = 0.f, cs1 = 0.f, cs2 = 0.f, cs3 = 0.f;
    float hl0 = 0.f, hl1 = 0.f, hl2 = 0.f, hl3 = 0.f;
    f32x4 xg0, xg1, xg2, xg3;
    {
        int p0 = dir ? (S_ - 1) : 0;
        int4 tk = *reinterpret_cast<const int4*>(&tokl[p0][lg << 2]);
        xg0 = *reinterpret_cast<const f32x4*>(xtg + ((size_t)tk.x << 9) + (u << 2));
        xg1 = *reinterpret_cast<const f32x4*>(xtg + ((size_t)tk.y << 9) + (u << 2));
        xg2 = *reinterpret_cast<const f32x4*>(xtg + ((size_t)tk.z << 9) + (u << 2));
        xg3 = *reinterpret_cast<const f32x4*>(xtg + ((size_t)tk.w << 9) + (u << 2));
    }

    const int arow = col;                 // A-fragment row = lane&15
    const int sw = (arow & 7) << 3;       // XOR swizzle (ushort units)
    const int abase = arow * 128;
    // flush mapping: thread -> 4 consecutive ushorts of h
    const int frow = tid >> 5;            // 0..15
    const int fu0 = (tid & 31) << 2;      // 0,4,..,124
    const int fdw = frow * 64 + (((tid & 31) << 1) ^ ((frow & 7) << 2));  // dword idx in plane
    ushort_t* const hs_row = hs + (size_t)(b0 + frow) * S_ * 256 + dir * 128 + fu0;

    for (int t = 0; t < S_; ++t) {
        const int cb = t & 1, nb = cb ^ 1;

        // acc init = xg (i,f,g,o per row)
        f32x4 acc0 = {xg0[0], xg1[0], xg2[0], xg3[0]};
        f32x4 acc1 = {xg0[1], xg1[1], xg2[1], xg3[1]};
        f32x4 acc2 = {xg0[2], xg1[2], xg2[2], xg3[2]};
        f32x4 acc3 = {xg0[3], xg1[3], xg2[3], xg3[3]};

        // coalesced flush of h_{t-1} (lives in hA[cb], hi plane) -- issued early
        if (t > 0) {
            int pos_prev = dir ? (S_ - t) : (t - 1);
            uint2 dd = *reinterpret_cast<const uint2*>((const uint_t*)&hA[cb][0][0] + fdw);
            *reinterpret_cast<uint2*>(hs_row + (size_t)pos_prev * 256) = dd;
        }

        // prefetch next step's xg -- issued early, consumed next step
        if (t + 1 < S_) {
            int pn = dir ? (S_ - 2 - t) : (t + 1);
            int4 tk = *reinterpret_cast<const int4*>(&tokl[pn][lg << 2]);
            xg0 = *reinterpret_cast<const f32x4*>(xtg + ((size_t)tk.x << 9) + (u << 2));
            xg1 = *reinterpret_cast<const f32x4*>(xtg + ((size_t)tk.y << 9) + (u << 2));
            xg2 = *reinterpret_cast<const f32x4*>(xtg + ((size_t)tk.z << 9) + (u << 2));
            xg3 = *reinterpret_cast<const f32x4*>(xtg + ((size_t)tk.w << 9) + (u << 2));
        }

        const ushort_t* hb_hi = &hA[cb][0][0];
        const ushort_t* hb_lo = &hA[cb][1][0];
        #define KT(kt) { \
            int ai = abase + ((((kt) << 5) + (lg << 3)) ^ sw); \
            bfrag ah = *reinterpret_cast<const bfrag*>(hb_hi + ai); \
            bfrag al = *reinterpret_cast<const bfrag*>(hb_lo + ai); \
            acc0 = __builtin_amdgcn_mfma_f32_16x16x32_bf16(ah, bh[0][kt], acc0, 0, 0, 0); \
            acc1 = __builtin_amdgcn_mfma_f32_16x16x32_bf16(ah, bh[1][kt], acc1, 0, 0, 0); \
            acc2 = __builtin_amdgcn_mfma_f32_16x16x32_bf16(ah, bh[2][kt], acc2, 0, 0, 0); \
            acc3 = __builtin_amdgcn_mfma_f32_16x16x32_bf16(ah, bh[3][kt], acc3, 0, 0, 0); \
            acc0 = __builtin_amdgcn_mfma_f32_16x16x32_bf16(ah, bl[0][kt], acc0, 0, 0, 0); \
            acc1 = __builtin_amdgcn_mfma_f32_16x16x32_bf16(ah, bl[1][kt], acc1, 0, 0, 0); \
            acc2 = __builtin_amdgcn_mfma_f32_16x16x32_bf16(ah, bl[2][kt], acc2, 0, 0, 0); \
            acc3 = __builtin_amdgcn_mfma_f32_16x16x32_bf16(ah, bl[3][kt], acc3, 0, 0, 0); \
            acc0 = __builtin_amdgcn_mfma_f32_16x16x32_bf16(al, bh[0][kt], acc0, 0, 0, 0); \
            acc1 = __builtin_amdgcn_mfma_f32_16x16x32_bf16(al, bh[1][kt], acc1, 0, 0, 0); \
            acc2 = __builtin_amdgcn_mfma_f32_16x16x32_bf16(al, bh[2][kt], acc2, 0, 0, 0); \
            acc3 = __builtin_amdgcn_mfma_f32_16x16x32_bf16(al, bh[3][kt], acc3, 0, 0, 0); \
        }
        KT(0) KT(1) KT(2) KT(3)
        #undef KT

        #define CELL(r, CSV, HLV) { \
            float gi = acc0[r], gf = acc1[r], gg = acc2[r], go = acc3[r]; \
            float ii = sigm(gi), ff = sigm(gf), gG = tanh_(gg), oo = sigm(go); \
            CSV = ff * CSV + ii * gG; \
            float h = oo * tanh_(CSV); \
            HLV = h; \
            int row = (lg << 2) + (r); \
            ushort_t hi = f2bf(h); \
            ushort_t lo = f2bf(h - __uint_as_float((uint_t)hi << 16)); \
            int wi = row * 128 + (u ^ ((row & 7) << 3)); \
            hA[nb][0][wi] = hi; hA[nb][1][wi] = lo; \
        }
        CELL(0, cs0, hl0) CELL(1, cs1, hl1) CELL(2, cs2, hl2) CELL(3, cs3, hl3)
        #undef CELL

        __syncthreads();
    }

    // final flush: h_{S-1} is in hA[0] (t=255: nb=0)
    {
        int pos_last = dir ? 0 : (S_ - 1);
        uint2 dd = *reinterpret_cast<const uint2*>((const uint_t*)&hA[0][0][0] + fdw);
        *reinterpret_cast<uint2*>(hs_row + (size_t)pos_last * 256) = dd;
    }

    #define FIN(r, CSV, HLV) { \
        int row = (lg << 2) + (r); \
        hfin[dir * 65536 + (b0 + row) * 128 + u] = HLV; \
        cfin[dir * 65536 + (b0 + row) * 128 + u] = CSV; }
    FIN(0, cs0, hl0) FIN(1, cs1, hl1) FIN(2, cs2, hl2) FIN(3, cs3, hl3)
    #undef FIN
}

// ---------------- decoder LSTM only: 10 steps, store hdec[b][t][128] ----------------
__global__ __launch_bounds__(512, 1) void dec_lstm_kernel(
    const int* __restrict__ target,
    const float* __restrict__ xt_d,
    const float* __restrict__ WhhT_d,
    const float* __restrict__ hfin, const float* __restrict__ cfin,
    float* __restrict__ hdec)
{
    const int b0 = blockIdx.x * 2;
    const int tid = threadIdx.x;
    const int j = tid;

    __shared__ __align__(16) float h_lds[2][128];
    __shared__ __align__(16) float g_lds[2][512];

    float4 w4[32];
    #pragma unroll
    for (int kc = 0; kc < 32; ++kc) {
        w4[kc].x = WhhT_d[(kc * 4 + 0) * 512 + j];
        w4[kc].y = WhhT_d[(kc * 4 + 1) * 512 + j];
        w4[kc].z = WhhT_d[(kc * 4 + 2) * 512 + j];
        w4[kc].w = WhhT_d[(kc * 4 + 3) * 512 + j];
    }
    const int r1 = tid >> 7, u1 = tid & 127;
    float c = 0.f;
    if (tid < 256) {
        int b = b0 + r1;
        c = cfin[b * 128 + u1] + cfin[65536 + b * 128 + u1];
        h_lds[r1][u1] = hfin[b * 128 + u1] + hfin[65536 + b * 128 + u1];
    }
    __syncthreads();

    for (int t = 0; t < T_; ++t) {
        int tok0 = (t == 0) ? 0 : target[(b0 + 0) * T_ + t - 1];
        int tok1 = (t == 0) ? 0 : target[(b0 + 1) * T_ + t - 1];
        float a0 = xt_d[tok0 * 512 + j];
        float a1 = xt_d[tok1 * 512 + j];
        #pragma unroll
        for (int kc = 0; kc < 32; ++kc) {
            const float4 w = w4[kc];
            const float4 h0 = *reinterpret_cast<const float4*>(&h_lds[0][kc * 4]);
            const float4 h1 = *reinterpret_cast<const float4*>(&h_lds[1][kc * 4]);
            a0 = fmaf(h0.x, w.x, a0); a0 = fmaf(h0.y, w.y, a0); a0 = fmaf(h0.z, w.z, a0); a0 = fmaf(h0.w, w.w, a0);
            a1 = fmaf(h1.x, w.x, a1); a1 = fmaf(h1.y, w.y, a1); a1 = fmaf(h1.z, w.z, a1); a1 = fmaf(h1.w, w.w, a1);
        }
        g_lds[0][j] = a0; g_lds[1][j] = a1;
        __syncthreads();
        if (tid < 256) {
            float gi = g_lds[r1][u1], gf = g_lds[r1][u1 + 128];
            float gg = g_lds[r1][u1 + 256], go = g_lds[r1][u1 + 384];
            float ii = sigm(gi), ff = sigm(gf), g_ = tanh_(gg), oo = sigm(go);
            c = ff * c + ii * g_;
            float h = oo * tanh_(c);
            h_lds[r1][u1] = h;
            hdec[((size_t)(b0 + r1) * T_ + t) * 128 + u1] = h;
        }
        __syncthreads();
    }
}

// ---------------- attention + output, batched over all 10 t ----------------
__global__ __launch_bounds__(256, 2) void attn_kernel(
    const float* __restrict__ hdec,
    const float* __restrict__ projW, const float* __restrict__ proj_b,
    const float* __restrict__ projWT,
    const float* __restrict__ attn_WT, const float* __restrict__ attn_b,
    const float* __restrict__ out_WT, const float* __restrict__ out_b,
    const ushort_t* __restrict__ hs, float* __restrict__ out)
{
    const int b = blockIdx.x;
    const int tid = threadIdx.x;

    __shared__ __align__(16) float hd[1280];
    __shared__ __align__(16) float reg1[2560];
    __shared__ __align__(16) float sc[2560];
    __shared__ __align__(16) float part[10240];
    __shared__ __align__(16) float wsum[2560];

    const ushort_t* e = hs + (size_t)b * 65536;

    for (int i = tid; i < 1280; i += 256) hd[i] = hdec[(size_t)b * 1280 + i];
    __syncthreads();

    // phase 0: q[t][d] = sum_k hd[t][k] * projW[k][d]  (swizzle-stored)
    {
        float acc[10];
        #pragma unroll
        for (int t = 0; t < 10; ++t) acc[t] = 0.f;
        for (int k = 0; k < 128; ++k) {
            float pw = projW[k * 256 + tid];
            #pragma unroll
            for (int t = 0; t < 10; ++t) acc[t] = fmaf(hd[t * 128 + k], pw, acc[t]);
        }
        int swd = tid ^ ((((uint_t)tid >> 5) & 7) << 2);
        #pragma unroll
        for (int t = 0; t < 10; ++t) reg1[t * 256 + swd] = acc[t];
    }
    __syncthreads();

    // phase 1: scores[t][s] = e[s][:] . q[t][:]
    {
        const int w = tid >> 6, l = tid & 63;
        const int s3 = l >> 3, k8 = l & 7;
        for (int pass = 0; pass < 8; ++pass) {
            int s = w * 64 + pass * 8 + s3;
            const ushort_t* row = e + s * 256 + k8 * 32;
            uint4 e0 = *reinterpret_cast<const uint4*>(row);
            uint4 e1 = *reinterpret_cast<const uint4*>(row + 8);
            uint4 e2 = *reinterpret_cast<const uint4*>(row + 16);
            uint4 e3 = *reinterpret_cast<const uint4*>(row + 24);
            float acc[10];
            #pragma unroll
            for (int t = 0; t < 10; ++t) {
                const float* qb = &reg1[t * 256];
                float a = 0.f;
                #define QCH(i) (*reinterpret_cast<const float4*>(&qb[(k8 * 32 + (i) * 4) ^ (k8 << 2)]))
                #define DOT4(pa, pb, qv) { float4 q_ = (qv); \
                    a = fmaf(bflo(pa), q_.x, a); a = fmaf(bfhi(pa), q_.y, a); \
                    a = fmaf(bflo(pb), q_.z, a); a = fmaf(bfhi(pb), q_.w, a); }
                DOT4(e0.x, e0.y, QCH(0)); DOT4(e0.z, e0.w, QCH(1));
                DOT4(e1.x, e1.y, QCH(2)); DOT4(e1.z, e1.w, QCH(3));
                DOT4(e2.x, e2.y, QCH(4)); DOT4(e2.z, e2.w, QCH(5));
                DOT4(e3.x, e3.y, QCH(6)); DOT4(e3.z, e3.w, QCH(7));
                #undef QCH
                #undef DOT4
                acc[t] = a;
            }
            #pragma unroll
            for (int t = 0; t < 10; ++t) {
                acc[t] += __shfl_xor(acc[t], 1);
                acc[t] += __shfl_xor(acc[t], 2);
                acc[t] += __shfl_xor(acc[t], 4);
            }
            if (k8 == 0) {
                #pragma unroll
                for (int t = 0; t < 10; ++t) sc[t * 256 + s] = acc[t];
            }
        }
    }
    __syncthreads();

    // phase 2: softmax
    {
        const int w = tid >> 6, l = tid & 63;
        for (int t = w; t < 10; t += 4) {
            float4 sv = *reinterpret_cast<const float4*>(&sc[t * 256 + l * 4]);
            float m = fmaxf(fmaxf(sv.x, sv.y), fmaxf(sv.z, sv.w));
            #pragma unroll
            for (int o = 1; o < 64; o <<= 1) m = fmaxf(m, __shfl_xor(m, o));
            float e0 = fast_exp2((sv.x - m) * 1.4426950408889634f);
            float e1 = fast_exp2((sv.y - m) * 1.4426950408889634f);
            float e2 = fast_exp2((sv.z - m) * 1.4426950408889634f);
            float e3 = fast_exp2((sv.w - m) * 1.4426950408889634f);
            float ssum = e0 + e1 + e2 + e3;
            #pragma unroll
            for (int o = 1; o < 64; o <<= 1) ssum += __shfl_xor(ssum, o);
            float inv = fast_rcp(ssum);
            *reinterpret_cast<float4*>(&sc[t * 256 + l * 4]) =
                make_float4(e0 * inv, e1 * inv, e2 * inv, e3 * inv);
        }
    }
    __syncthreads();

    // phase 3: wsum partials
    {
        const int w = tid >> 6, l = tid & 63;
        float ax[10], ay[10], az[10], aw2[10];
        #pragma unroll
        for (int t = 0; t < 10; ++t) { ax[t] = 0.f; ay[t] = 0.f; az[t] = 0.f; aw2[t] = 0.f; }
        const ushort_t* col = e + l * 4;
        for (int s = w * 64; s < w * 64 + 64; ++s) {
            uint2 uu = *reinterpret_cast<const uint2*>(col + (size_t)s * 256);
            float v0 = bflo(uu.x), v1 = bfhi(uu.x), v2 = bflo(uu.y), v3 = bfhi(uu.y);
            #pragma unroll
            for (int t = 0; t < 10; ++t) {
                float awv = sc[t * 256 + s];
                ax[t] = fmaf(v0, awv, ax[t]); ay[t] = fmaf(v1, awv, ay[t]);
                az[t] = fmaf(v2, awv, az[t]); aw2[t] = fmaf(v3, awv, aw2[t]);
            }
        }
        #pragma unroll
        for (int t = 0; t < 10; ++t)
            *reinterpret_cast<float4*>(&part[(w * 10 + t) * 256 + l * 4]) =
                make_float4(ax[t], ay[t], az[t], aw2[t]);
    }
    __syncthreads();

    // phase 4: reduce partials
    for (int i = tid; i < 2560; i += 256)
        wsum[i] = part[i] + part[2560 + i] + part[5120 + i] + part[7680 + i];
    __syncthreads();

    // phase 5: ctx
    {
        const int u = tid & 127, th = tid >> 7;
        float acc[5];
        #pragma unroll
        for (int i = 0; i < 5; ++i) acc[i] = proj_b[u];
        for (int k = 0; k < 256; ++k) {
            float pw = projWT[k * 128 + u];
            #pragma unroll
            for (int i = 0; i < 5; ++i) acc[i] = fmaf(pw, wsum[(th * 5 + i) * 256 + k], acc[i]);
        }
        #pragma unroll
        for (int i = 0; i < 5; ++i) reg1[(th * 5 + i) * 128 + u] = acc[i];
    }
    __syncthreads();

    // phase 6: comb
    {
        const int u = tid & 127, th = tid >> 7;
        float acc[5];
        #pragma unroll
        for (int i = 0; i < 5; ++i) acc[i] = attn_b[u];
        for (int k = 0; k < 128; ++k) {
            float a1 = attn_WT[k * 128 + u];
            #pragma unroll
            for (int i = 0; i < 5; ++i) acc[i] = fmaf(a1, hd[(th * 5 + i) * 128 + k], acc[i]);
        }
        for (int k = 0; k < 128; ++k) {
            float a2 = attn_WT[(128 + k) * 128 + u];
            #pragma unroll
            for (int i = 0; i < 5; ++i) acc[i] = fmaf(a2, reg1[(th * 5 + i) * 128 + k], acc[i]);
        }
        #pragma unroll
        for (int i = 0; i < 5; ++i) reg1[1280 + (th * 5 + i) * 128 + u] = tanh_(acc[i]);
    }
    __syncthreads();

    // phase 7: logits
    for (int o = tid; o < 280; o += 256) {
        int t = o / 28, v = o - t * 28;
        float acc = out_b[v];
        #pragma unroll 4
        for (int k = 0; k < 128; ++k)
            acc = fmaf(out_WT[k * 28 + v], reg1[1280 + t * 128 + k], acc);
        out[(size_t)b * 280 + o] = acc;
    }
}

extern "C" void kernel_launch(void* const* d_in, const int* in_sizes, int n_in,
                              void* d_out, int out_size, void* d_ws, size_t ws_size,
                              hipStream_t stream) {
    const int* src      = (const int*)d_in[0];
    const int* target   = (const int*)d_in[1];
    const float* embed  = (const float*)d_in[2];
    const float* Wih_f  = (const float*)d_in[3];
    const float* Whh_f  = (const float*)d_in[4];
    const float* b_f    = (const float*)d_in[5];
    const float* Wih_b  = (const float*)d_in[6];
    const float* Whh_b  = (const float*)d_in[7];
    const float* b_b    = (const float*)d_in[8];
    const float* Wih_d  = (const float*)d_in[9];
    const float* Whh_d  = (const float*)d_in[10];
    const float* b_d    = (const float*)d_in[11];
    const float* proj_W = (const float*)d_in[12];
    const float* proj_b = (const float*)d_in[13];
    const float* attn_W = (const float*)d_in[14];
    const float* attn_b = (const float*)d_in[15];
    const float* out_W  = (const float*)d_in[16];
    const float* out_b  = (const float*)d_in[17];

    float* ws = (float*)d_ws;
    ushort_t* hs = (ushort_t*)((char*)d_ws + HS_BYTE_OFF);
    float* out = (float*)d_out;

    prep_kernel<<<(PREP_N + 255) / 256, 256, 0, stream>>>(
        embed, Wih_f, b_f, Wih_b, b_b, Wih_d, b_d,
        Whh_f, Whh_b, Whh_d, attn_W, out_W, proj_W, ws);

    enc_kernel<<<64, 512, 0, stream>>>(
        src, ws + XTG, (const ushort_t*)(ws + WPK),
        ws + HFIN, ws + CFIN, hs);

    dec_lstm_kernel<<<256, 512, 0, stream>>>(
        target, ws + XTD, ws + WTD, ws + HFIN, ws + CFIN, ws + HDEC);

    attn_kernel<<<512, 256, 0, stream>>>(
        ws + HDEC, proj_W, proj_b, ws + PWT, ws + AWT, attn_b,
        ws + OWT, out_b, hs, out);
}

// Round 6
// 531.387 us; speedup vs baseline: 1.5442x; 1.0237x over previous
//
#include <hip/hip_runtime.h>
#include <hip/hip_bf16.h>
#include <stdint.h>

typedef unsigned short ushort_t;
typedef unsigned int uint_t;
typedef __attribute__((ext_vector_type(8))) short bfrag;   // 8 bf16 = 4 VGPR
typedef __attribute__((ext_vector_type(4))) float f32x4;

#define B_ 512
#define S_ 256
#define T_ 10
#define V_ 28
#define H_ 128

// ---- workspace layout (float element offsets) ----
#define XTD 0         // dec xg table [28][512]
#define XTG 14336     // enc xg gate-interleaved [2][28][128][4]
#define WTD 43008     // dec WhhT [128][512]
#define AWT 108544    // attn_WT [256][128]
#define OWT 141312    // out_WT [128][28]
#define PWT 144896    // projWT [256][128]
#define WPK 177664    // enc W bf16x2 frag-packed, 262144 ushort
#define HFIN 308736
#define CFIN 439808
#define HDEC 570880
#define HS_BYTE_OFF (1226240ull * 4ull)
#define PREP_N 439808

__device__ __forceinline__ float fast_exp2(float x) { return __builtin_amdgcn_exp2f(x); }
__device__ __forceinline__ float fast_rcp(float x)  { return __builtin_amdgcn_rcpf(x); }
__device__ __forceinline__ float sigm(float x) {
    return fast_rcp(1.f + fast_exp2(-1.4426950408889634f * x));
}
__device__ __forceinline__ float tanh_(float x) {
    return 1.f - 2.f * fast_rcp(1.f + fast_exp2(2.8853900817779268f * x));
}
__device__ __forceinline__ ushort_t f2bf(float x) {
    uint_t u = __float_as_uint(x);
    return (ushort_t)((u + 0x7FFFu + ((u >> 16) & 1u)) >> 16);  // RNE
}
__device__ __forceinline__ float bflo(uint_t u) { return __uint_as_float(u << 16); }
__device__ __forceinline__ float bfhi(uint_t u) { return __uint_as_float(u & 0xFFFF0000u); }

// ---------------- prep ----------------
__global__ __launch_bounds__(256) void prep_kernel(
    const float* __restrict__ embed,
    const float* __restrict__ Wih_f, const float* __restrict__ b_f,
    const float* __restrict__ Wih_b, const float* __restrict__ b_b,
    const float* __restrict__ Wih_d, const float* __restrict__ b_d,
    const float* __restrict__ Whh_f, const float* __restrict__ Whh_b,
    const float* __restrict__ Whh_d,
    const float* __restrict__ attn_W, const float* __restrict__ out_W,
    const float* __restrict__ proj_W,
    float* __restrict__ ws)
{
    int i = blockIdx.x * 256 + threadIdx.x;
    if (i < XTG) {                         // dec xg table: [v][j]
        int v = i >> 9, jj = i & 511;
        float acc = b_d[jj];
        #pragma unroll
        for (int e = 0; e < 32; ++e) acc = fmaf(embed[v * 32 + e], Wih_d[jj * 32 + e], acc);
        ws[XTD + i] = acc;
    } else if (i < WTD) {                  // enc xg gate-interleaved: [d][v][u][g]
        int r = i - XTG; int d = r / 14336; int rem = r % 14336;
        int v = rem >> 9, q = rem & 511;
        int uu = q >> 2, g = q & 3;
        int jj = g * 128 + uu;
        const float* Wih = d ? Wih_b : Wih_f;
        const float* bb  = d ? b_b   : b_f;
        float acc = bb[jj];
        #pragma unroll
        for (int e = 0; e < 32; ++e) acc = fmaf(embed[v * 32 + e], Wih[jj * 32 + e], acc);
        ws[XTG + r] = acc;
    } else if (i < AWT) {                  // dec WhhT[k][j]
        int r = i - WTD; int k = r >> 9, jj = r & 511;
        ws[WTD + r] = Whh_d[jj * 128 + k];
    } else if (i < OWT) {                  // attn_WT[k][u]
        int r = i - AWT; int k = r >> 7, uu = r & 127;
        ws[i] = attn_W[uu * 256 + k];
    } else if (i < PWT) {                  // out_WT[k][v]
        int r = i - OWT; int k = r / 28, v = r % 28;
        ws[i] = out_W[v * 128 + k];
    } else if (i < WPK) {                  // projWT[k][u]
        int r = i - PWT; int k = r >> 7, uu = r & 127;
        ws[i] = proj_W[uu * 256 + k];
    } else if (i < PREP_N) {               // enc weight frag pack (bf16 hi/lo)
        int i2 = i - WPK;
        int e  = i2 & 7;
        int ll = (i2 >> 3) & 63;
        int p  = (i2 >> 9) & 1;
        int kt = (i2 >> 10) & 3;
        int ni = (i2 >> 12) & 3;
        int wv = (i2 >> 14) & 7;
        int d  = (i2 >> 17) & 1;
        int jj = (ni * 8 + wv) * 16 + (ll & 15);   // gate column (N)
        int k  = kt * 32 + (ll >> 4) * 8 + e;      // K index
        const float* Whh = d ? Whh_b : Whh_f;
        float Wv = Whh[jj * 128 + k];
        ushort_t hi = f2bf(Wv);
        ushort_t ov = p ? f2bf(Wv - __uint_as_float((uint_t)hi << 16)) : hi;
        ((ushort_t*)(ws + WPK))[i2] = ov;
    }
}

// ---------------- encoder: MFMA, 4 rows/block, 256 blocks (1 per CU), 8 waves ----------------
// M=16 MFMA tile zero-padded (rows 4..15 stay 0 in hA, never rewritten).
// Gates redistributed via g_lds so each thread computes exactly ONE cell
// (10 transcendentals/thread/step instead of 40).
__global__ __launch_bounds__(512, 2) void enc_kernel(
    const int* __restrict__ src,
    const float* __restrict__ xtg_base,     // ws+XTG
    const ushort_t* __restrict__ wpk,       // ws+WPK
    float* __restrict__ hfin, float* __restrict__ cfin,
    ushort_t* __restrict__ hs)
{
    const int bx = blockIdx.x;
    const int dir = bx >> 7;
    const int b0 = (bx & 127) << 2;
    const int tid = threadIdx.x;
    const int w = tid >> 6, l = tid & 63;
    const int lg = l >> 4, col = l & 15;
    const int u = (w << 4) + col;

    __shared__ ushort_t hA[2][2][2048];           // [buf][hi/lo][row*128 + swizzled u]
    __shared__ __align__(16) int tokl[256][4];    // [s][row]
    __shared__ __align__(16) float g_lds[4][4][128]; // [gate][row][u]

    for (int i = tid; i < 1024; i += 512)
        tokl[i >> 2][i & 3] = src[(b0 + (i & 3)) * S_ + (i >> 2)];
    for (int i = tid; i < 4096; i += 512) ((uint_t*)hA)[i] = 0u;

    const float* xtg = xtg_base + dir * 14336;

    // persistent B fragments: 4 N-tiles x 4 K-tiles x {hi,lo} = 128 regs
    bfrag bh[4][4], bl[4][4];
    {
        const ushort_t* wb = wpk + (((size_t)dir * 8 + w) << 14) + l * 8;
        #pragma unroll
        for (int ni = 0; ni < 4; ++ni)
            #pragma unroll
            for (int kt = 0; kt < 4; ++kt) {
                bh[ni][kt] = *reinterpret_cast<const bfrag*>(wb + (((ni * 4 + kt) * 2 + 0) << 9));
                bl[ni][kt] = *reinterpret_cast<const bfrag*>(wb + (((ni * 4 + kt) * 2 + 1) << 9));
            }
    }
    __syncthreads();

    // per-thread cell state: thread -> (crow = tid>>7, cu = tid&127)
    const int crow = tid >> 7, cu = tid & 127;
    float c_reg = 0.f, h_reg = 0.f;

    f32x4 xg0, xg1, xg2, xg3;
    {
        int p0 = dir ? (S_ - 1) : 0;
        int4 tk = *reinterpret_cast<const int4*>(&tokl[p0][0]);
        xg0 = *reinterpret_cast<const f32x4*>(xtg + ((size_t)tk.x << 9) + (u << 2));
        xg1 = *reinterpret_cast<const f32x4*>(xtg + ((size_t)tk.y << 9) + (u << 2));
        xg2 = *reinterpret_cast<const f32x4*>(xtg + ((size_t)tk.z << 9) + (u << 2));
        xg3 = *reinterpret_cast<const f32x4*>(xtg + ((size_t)tk.w << 9) + (u << 2));
    }

    const int arow = col;                 // A-fragment row = lane&15
    const int sw = (arow & 7) << 3;       // XOR swizzle (ushort units)
    const int abase = arow * 128;

    for (int t = 0; t < S_; ++t) {
        const int cb = t & 1, nb = cb ^ 1;

        // acc init = xg (i,f,g,o per row; rows 4..15 garbage-but-harmless)
        f32x4 acc0 = {xg0[0], xg1[0], xg2[0], xg3[0]};
        f32x4 acc1 = {xg0[1], xg1[1], xg2[1], xg3[1]};
        f32x4 acc2 = {xg0[2], xg1[2], xg2[2], xg3[2]};
        f32x4 acc3 = {xg0[3], xg1[3], xg2[3], xg3[3]};

        // prefetch next step's xg early (consumed next step)
        if (t + 1 < S_) {
            int pn = dir ? (S_ - 2 - t) : (t + 1);
            int4 tk = *reinterpret_cast<const int4*>(&tokl[pn][0]);
            xg0 = *reinterpret_cast<const f32x4*>(xtg + ((size_t)tk.x << 9) + (u << 2));
            xg1 = *reinterpret_cast<const f32x4*>(xtg + ((size_t)tk.y << 9) + (u << 2));
            xg2 = *reinterpret_cast<const f32x4*>(xtg + ((size_t)tk.z << 9) + (u << 2));
            xg3 = *reinterpret_cast<const f32x4*>(xtg + ((size_t)tk.w << 9) + (u << 2));
        }

        const ushort_t* hb_hi = &hA[cb][0][0];
        const ushort_t* hb_lo = &hA[cb][1][0];
        #define KT(kt) { \
            int ai = abase + ((((kt) << 5) + (lg << 3)) ^ sw); \
            bfrag ah = *reinterpret_cast<const bfrag*>(hb_hi + ai); \
            bfrag al = *reinterpret_cast<const bfrag*>(hb_lo + ai); \
            acc0 = __builtin_amdgcn_mfma_f32_16x16x32_bf16(ah, bh[0][kt], acc0, 0, 0, 0); \
            acc1 = __builtin_amdgcn_mfma_f32_16x16x32_bf16(ah, bh[1][kt], acc1, 0, 0, 0); \
            acc2 = __builtin_amdgcn_mfma_f32_16x16x32_bf16(ah, bh[2][kt], acc2, 0, 0, 0); \
            acc3 = __builtin_amdgcn_mfma_f32_16x16x32_bf16(ah, bh[3][kt], acc3, 0, 0, 0); \
            acc0 = __builtin_amdgcn_mfma_f32_16x16x32_bf16(ah, bl[0][kt], acc0, 0, 0, 0); \
            acc1 = __builtin_amdgcn_mfma_f32_16x16x32_bf16(ah, bl[1][kt], acc1, 0, 0, 0); \
            acc2 = __builtin_amdgcn_mfma_f32_16x16x32_bf16(ah, bl[2][kt], acc2, 0, 0, 0); \
            acc3 = __builtin_amdgcn_mfma_f32_16x16x32_bf16(ah, bl[3][kt], acc3, 0, 0, 0); \
            acc0 = __builtin_amdgcn_mfma_f32_16x16x32_bf16(al, bh[0][kt], acc0, 0, 0, 0); \
            acc1 = __builtin_amdgcn_mfma_f32_16x16x32_bf16(al, bh[1][kt], acc1, 0, 0, 0); \
            acc2 = __builtin_amdgcn_mfma_f32_16x16x32_bf16(al, bh[2][kt], acc2, 0, 0, 0); \
            acc3 = __builtin_amdgcn_mfma_f32_16x16x32_bf16(al, bh[3][kt], acc3, 0, 0, 0); \
        }
        KT(0) KT(1) KT(2) KT(3)
        #undef KT

        // scatter the 4 real rows' gates to g_lds (lanes with lg==0 hold them)
        if (lg == 0) {
            #pragma unroll
            for (int j = 0; j < 4; ++j) {
                g_lds[0][j][u] = acc0[j];
                g_lds[1][j][u] = acc1[j];
                g_lds[2][j][u] = acc2[j];
                g_lds[3][j][u] = acc3[j];
            }
        }
        __syncthreads();

        // cell: one per thread
        {
            float gi = g_lds[0][crow][cu], gf = g_lds[1][crow][cu];
            float gg = g_lds[2][crow][cu], go = g_lds[3][crow][cu];
            float ii = sigm(gi), ff = sigm(gf), gG = tanh_(gg), oo = sigm(go);
            c_reg = ff * c_reg + ii * gG;
            float h = oo * tanh_(c_reg);
            h_reg = h;
            ushort_t hi = f2bf(h);
            ushort_t lo = f2bf(h - __uint_as_float((uint_t)hi << 16));
            int wi = crow * 128 + (cu ^ (crow << 3));   // crow<4 so (crow&7)=crow
            hA[nb][0][wi] = hi; hA[nb][1][wi] = lo;
            int pos = dir ? (S_ - 1 - t) : t;
            hs[((size_t)(b0 + crow) * S_ + pos) * 256 + dir * 128 + cu] = hi;
        }
        __syncthreads();
    }

    hfin[dir * 65536 + (b0 + crow) * 128 + cu] = h_reg;
    cfin[dir * 65536 + (b0 + crow) * 128 + cu] = c_reg;
}

// ---------------- decoder LSTM only: 10 steps, store hdec[b][t][128] ----------------
__global__ __launch_bounds__(512, 1) void dec_lstm_kernel(
    const int* __restrict__ target,
    const float* __restrict__ xt_d,
    const float* __restrict__ WhhT_d,
    const float* __restrict__ hfin, const float* __restrict__ cfin,
    float* __restrict__ hdec)
{
    const int b0 = blockIdx.x * 2;
    const int tid = threadIdx.x;
    const int j = tid;

    __shared__ __align__(16) float h_lds[2][128];
    __shared__ __align__(16) float g_lds[2][512];

    float4 w4[32];
    #pragma unroll
    for (int kc = 0; kc < 32; ++kc) {
        w4[kc].x = WhhT_d[(kc * 4 + 0) * 512 + j];
        w4[kc].y = WhhT_d[(kc * 4 + 1) * 512 + j];
        w4[kc].z = WhhT_d[(kc * 4 + 2) * 512 + j];
        w4[kc].w = WhhT_d[(kc * 4 + 3) * 512 + j];
    }
    const int r1 = tid >> 7, u1 = tid & 127;
    float c = 0.f;
    if (tid < 256) {
        int b = b0 + r1;
        c = cfin[b * 128 + u1] + cfin[65536 + b * 128 + u1];
        h_lds[r1][u1] = hfin[b * 128 + u1] + hfin[65536 + b * 128 + u1];
    }
    __syncthreads();

    for (int t = 0; t < T_; ++t) {
        int tok0 = (t == 0) ? 0 : target[(b0 + 0) * T_ + t - 1];
        int tok1 = (t == 0) ? 0 : target[(b0 + 1) * T_ + t - 1];
        float a0 = xt_d[tok0 * 512 + j];
        float a1 = xt_d[tok1 * 512 + j];
        #pragma unroll
        for (int kc = 0; kc < 32; ++kc) {
            const float4 w = w4[kc];
            const float4 h0 = *reinterpret_cast<const float4*>(&h_lds[0][kc * 4]);
            const float4 h1 = *reinterpret_cast<const float4*>(&h_lds[1][kc * 4]);
            a0 = fmaf(h0.x, w.x, a0); a0 = fmaf(h0.y, w.y, a0); a0 = fmaf(h0.z, w.z, a0); a0 = fmaf(h0.w, w.w, a0);
            a1 = fmaf(h1.x, w.x, a1); a1 = fmaf(h1.y, w.y, a1); a1 = fmaf(h1.z, w.z, a1); a1 = fmaf(h1.w, w.w, a1);
        }
        g_lds[0][j] = a0; g_lds[1][j] = a1;
        __syncthreads();
        if (tid < 256) {
            float gi = g_lds[r1][u1], gf = g_lds[r1][u1 + 128];
            float gg = g_lds[r1][u1 + 256], go = g_lds[r1][u1 + 384];
            float ii = sigm(gi), ff = sigm(gf), g_ = tanh_(gg), oo = sigm(go);
            c = ff * c + ii * g_;
            float h = oo * tanh_(c);
            h_lds[r1][u1] = h;
            hdec[((size_t)(b0 + r1) * T_ + t) * 128 + u1] = h;
        }
        __syncthreads();
    }
}

// ---------------- attention + output, batched over all 10 t ----------------
__global__ __launch_bounds__(256, 2) void attn_kernel(
    const float* __restrict__ hdec,
    const float* __restrict__ projW, const float* __restrict__ proj_b,
    const float* __restrict__ projWT,
    const float* __restrict__ attn_WT, const float* __restrict__ attn_b,
    const float* __restrict__ out_WT, const float* __restrict__ out_b,
    const ushort_t* __restrict__ hs, float* __restrict__ out)
{
    const int b = blockIdx.x;
    const int tid = threadIdx.x;

    __shared__ __align__(16) float hd[1280];
    __shared__ __align__(16) float reg1[2560];
    __shared__ __align__(16) float sc[2560];
    __shared__ __align__(16) float part[10240];
    __shared__ __align__(16) float wsum[2560];

    const ushort_t* e = hs + (size_t)b * 65536;

    for (int i = tid; i < 1280; i += 256) hd[i] = hdec[(size_t)b * 1280 + i];
    __syncthreads();

    // phase 0: q[t][d] = sum_k hd[t][k] * projW[k][d]  (swizzle-stored)
    {
        float acc[10];
        #pragma unroll
        for (int t = 0; t < 10; ++t) acc[t] = 0.f;
        for (int k = 0; k < 128; ++k) {
            float pw = projW[k * 256 + tid];
            #pragma unroll
            for (int t = 0; t < 10; ++t) acc[t] = fmaf(hd[t * 128 + k], pw, acc[t]);
        }
        int swd = tid ^ ((((uint_t)tid >> 5) & 7) << 2);
        #pragma unroll
        for (int t = 0; t < 10; ++t) reg1[t * 256 + swd] = acc[t];
    }
    __syncthreads();

    // phase 1: scores[t][s] = e[s][:] . q[t][:]
    {
        const int w = tid >> 6, l = tid & 63;
        const int s3 = l >> 3, k8 = l & 7;
        for (int pass = 0; pass < 8; ++pass) {
            int s = w * 64 + pass * 8 + s3;
            const ushort_t* row = e + s * 256 + k8 * 32;
            uint4 e0 = *reinterpret_cast<const uint4*>(row);
            uint4 e1 = *reinterpret_cast<const uint4*>(row + 8);
            uint4 e2 = *reinterpret_cast<const uint4*>(row + 16);
            uint4 e3 = *reinterpret_cast<const uint4*>(row + 24);
            float acc[10];
            #pragma unroll
            for (int t = 0; t < 10; ++t) {
                const float* qb = &reg1[t * 256];
                float a = 0.f;
                #define QCH(i) (*reinterpret_cast<const float4*>(&qb[(k8 * 32 + (i) * 4) ^ (k8 << 2)]))
                #define DOT4(pa, pb, qv) { float4 q_ = (qv); \
                    a = fmaf(bflo(pa), q_.x, a); a = fmaf(bfhi(pa), q_.y, a); \
                    a = fmaf(bflo(pb), q_.z, a); a = fmaf(bfhi(pb), q_.w, a); }
                DOT4(e0.x, e0.y, QCH(0)); DOT4(e0.z, e0.w, QCH(1));
                DOT4(e1.x, e1.y, QCH(2)); DOT4(e1.z, e1.w, QCH(3));
                DOT4(e2.x, e2.y, QCH(4)); DOT4(e2.z, e2.w, QCH(5));
                DOT4(e3.x, e3.y, QCH(6)); DOT4(e3.z, e3.w, QCH(7));
                #undef QCH
                #undef DOT4
                acc[t] = a;
            }
            #pragma unroll
            for (int t = 0; t < 10; ++t) {
                acc[t] += __shfl_xor(acc[t], 1);
                acc[t] += __shfl_xor(acc[t], 2);
                acc[t] += __shfl_xor(acc[t], 4);
            }
            if (k8 == 0) {
                #pragma unroll
                for (int t = 0; t < 10; ++t) sc[t * 256 + s] = acc[t];
            }
        }
    }
    __syncthreads();

    // phase 2: softmax
    {
        const int w = tid >> 6, l = tid & 63;
        for (int t = w; t < 10; t += 4) {
            float4 sv = *reinterpret_cast<const float4*>(&sc[t * 256 + l * 4]);
            float m = fmaxf(fmaxf(sv.x, sv.y), fmaxf(sv.z, sv.w));
            #pragma unroll
            for (int o = 1; o < 64; o <<= 1) m = fmaxf(m, __shfl_xor(m, o));
            float e0 = fast_exp2((sv.x - m) * 1.4426950408889634f);
            float e1 = fast_exp2((sv.y - m) * 1.4426950408889634f);
            float e2 = fast_exp2((sv.z - m) * 1.4426950408889634f);
            float e3 = fast_exp2((sv.w - m) * 1.4426950408889634f);
            float ssum = e0 + e1 + e2 + e3;
            #pragma unroll
            for (int o = 1; o < 64; o <<= 1) ssum += __shfl_xor(ssum, o);
            float inv = fast_rcp(ssum);
            *reinterpret_cast<float4*>(&sc[t * 256 + l * 4]) =
                make_float4(e0 * inv, e1 * inv, e2 * inv, e3 * inv);
        }
    }
    __syncthreads();

    // phase 3: wsum partials
    {
        const int w = tid >> 6, l = tid & 63;
        float ax[10], ay[10], az[10], aw2[10];
        #pragma unroll
        for (int t = 0; t < 10; ++t) { ax[t] = 0.f; ay[t] = 0.f; az[t] = 0.f; aw2[t] = 0.f; }
        const ushort_t* col = e + l * 4;
        for (int s = w * 64; s < w * 64 + 64; ++s) {
            uint2 uu = *reinterpret_cast<const uint2*>(col + (size_t)s * 256);
            float v0 = bflo(uu.x), v1 = bfhi(uu.x), v2 = bflo(uu.y), v3 = bfhi(uu.y);
            #pragma unroll
            for (int t = 0; t < 10; ++t) {
                float awv = sc[t * 256 + s];
                ax[t] = fmaf(v0, awv, ax[t]); ay[t] = fmaf(v1, awv, ay[t]);
                az[t] = fmaf(v2, awv, az[t]); aw2[t] = fmaf(v3, awv, aw2[t]);
            }
        }
        #pragma unroll
        for (int t = 0; t < 10; ++t)
            *reinterpret_cast<float4*>(&part[(w * 10 + t) * 256 + l * 4]) =
                make_float4(ax[t], ay[t], az[t], aw2[t]);
    }
    __syncthreads();

    // phase 4: reduce partials
    for (int i = tid; i < 2560; i += 256)
        wsum[i] = part[i] + part[2560 + i] + part[5120 + i] + part[7680 + i];
    __syncthreads();

    // phase 5: ctx
    {
        const int u = tid & 127, th = tid >> 7;
        float acc[5];
        #pragma unroll
        for (int i = 0; i < 5; ++i) acc[i] = proj_b[u];
        for (int k = 0; k < 256; ++k) {
            float pw = projWT[k * 128 + u];
            #pragma unroll
            for (int i = 0; i < 5; ++i) acc[i] = fmaf(pw, wsum[(th * 5 + i) * 256 + k], acc[i]);
        }
        #pragma unroll
        for (int i = 0; i < 5; ++i) reg1[(th * 5 + i) * 128 + u] = acc[i];
    }
    __syncthreads();

    // phase 6: comb
    {
        const int u = tid & 127, th = tid >> 7;
        float acc[5];
        #pragma unroll
        for (int i = 0; i < 5; ++i) acc[i] = attn_b[u];
        for (int k = 0; k < 128; ++k) {
            float a1 = attn_WT[k * 128 + u];
            #pragma unroll
            for (int i = 0; i < 5; ++i) acc[i] = fmaf(a1, hd[(th * 5 + i) * 128 + k], acc[i]);
        }
        for (int k = 0; k < 128; ++k) {
            float a2 = attn_WT[(128 + k) * 128 + u];
            #pragma unroll
            for (int i = 0; i < 5; ++i) acc[i] = fmaf(a2, reg1[(th * 5 + i) * 128 + k], acc[i]);
        }
        #pragma unroll
        for (int i = 0; i < 5; ++i) reg1[1280 + (th * 5 + i) * 128 + u] = tanh_(acc[i]);
    }
    __syncthreads();

    // phase 7: logits
    for (int o = tid; o < 280; o += 256) {
        int t = o / 28, v = o - t * 28;
        float acc = out_b[v];
        #pragma unroll 4
        for (int k = 0; k < 128; ++k)
            acc = fmaf(out_WT[k * 28 + v], reg1[1280 + t * 128 + k], acc);
        out[(size_t)b * 280 + o] = acc;
    }
}

extern "C" void kernel_launch(void* const* d_in, const int* in_sizes, int n_in,
                              void* d_out, int out_size, void* d_ws, size_t ws_size,
                              hipStream_t stream) {
    const int* src      = (const int*)d_in[0];
    const int* target   = (const int*)d_in[1];
    const float* embed  = (const float*)d_in[2];
    const float* Wih_f  = (const float*)d_in[3];
    const float* Whh_f  = (const float*)d_in[4];
    const float* b_f    = (const float*)d_in[5];
    const float* Wih_b  = (const float*)d_in[6];
    const float* Whh_b  = (const float*)d_in[7];
    const float* b_b    = (const float*)d_in[8];
    const float* Wih_d  = (const float*)d_in[9];
    const float* Whh_d  = (const float*)d_in[10];
    const float* b_d    = (const float*)d_in[11];
    const float* proj_W = (const float*)d_in[12];
    const float* proj_b = (const float*)d_in[13];
    const float* attn_W = (const float*)d_in[14];
    const float* attn_b = (const float*)d_in[15];
    const float* out_W  = (const float*)d_in[16];
    const float* out_b  = (const float*)d_in[17];

    float* ws = (float*)d_ws;
    ushort_t* hs = (ushort_t*)((char*)d_ws + HS_BYTE_OFF);
    float* out = (float*)d_out;

    prep_kernel<<<(PREP_N + 255) / 256, 256, 0, stream>>>(
        embed, Wih_f, b_f, Wih_b, b_b, Wih_d, b_d,
        Whh_f, Whh_b, Whh_d, attn_W, out_W, proj_W, ws);

    enc_kernel<<<256, 512, 0, stream>>>(
        src, ws + XTG, (const ushort_t*)(ws + WPK),
        ws + HFIN, ws + CFIN, hs);

    dec_lstm_kernel<<<256, 512, 0, stream>>>(
        target, ws + XTD, ws + WTD, ws + HFIN, ws + CFIN, ws + HDEC);

    attn_kernel<<<512, 256, 0, stream>>>(
        ws + HDEC, proj_W, proj_b, ws + PWT, ws + AWT, attn_b,
        ws + OWT, out_b, hs, out);
}